// Round 1
// 530.954 us; speedup vs baseline: 1.1776x; 1.1776x over previous
//
#include <hip/hip_runtime.h>
#include <hip/hip_bf16.h>

typedef __bf16 bf16;
typedef __bf16 bf16x8 __attribute__((ext_vector_type(8)));
typedef float  floatx4 __attribute__((ext_vector_type(4)));

#define AS1 __attribute__((address_space(1)))
#define AS3 __attribute__((address_space(3)))

#define B_    2
#define S_    2048
#define D_    2048
#define H_    16
#define KVH_  8
#define DH_   128
#define M_    4096      // B_*S_
#define NQKV_ 4096      // D_ + 2*KVH_*DH_

// ---------------------------------------------------------------- cast fp32 -> bf16
__global__ __launch_bounds__(256) void cast_kernel(const float* __restrict__ in,
                                                   bf16* __restrict__ out, int n) {
    int i = (blockIdx.x * blockDim.x + threadIdx.x) * 4;
    if (i < n) {
        float4 v = *(const float4*)(in + i);
        union { bf16 h[4]; double d; } u;
        u.h[0] = (bf16)v.x; u.h[1] = (bf16)v.y; u.h[2] = (bf16)v.z; u.h[3] = (bf16)v.w;
        *(double*)(out + i) = u.d;
    }
}

// ---------------------------------------------------------------- RoPE tables [S][64]
__global__ __launch_bounds__(256) void rope_table(float* __restrict__ cost,
                                                  float* __restrict__ sint) {
    int i = blockIdx.x * blockDim.x + threadIdx.x;   // S_*64 threads
    int t = i >> 6, fi = i & 63;
    float inv = expf(-9.210340371976184f * (float)fi * (1.0f / 64.0f)); // 10000^(-fi/64)
    float ang = (float)t * inv;
    cost[i] = cosf(ang);
    sint[i] = sinf(ang);
}

// ---------------------------------------------------------------- GEMM: C[M,N] = A[M,K] * B[N,K]^T   (bf16 in, fp32 acc, CT out)
#define BM 128
#define BN 128
#define BK 64
template <typename CT>
__global__ __launch_bounds__(256) void gemm_bt(const bf16* __restrict__ A,
                                               const bf16* __restrict__ Bw,
                                               CT* __restrict__ C,
                                               int M, int N, int K) {
    __shared__ __align__(16) bf16 Als[BM * BK];
    __shared__ __align__(16) bf16 Bls[BN * BK];
    int tid  = threadIdx.x;
    int wave = tid >> 6, lane = tid & 63;
    int quad = lane >> 4, l16 = lane & 15;
    int wm = (wave >> 1) << 6;   // 0 / 64
    int wn = (wave & 1) << 6;

    long bm0 = (long)blockIdx.y * BM;
    long bn0 = (long)blockIdx.x * BN;
    const bf16* Ab = A  + bm0 * K;
    const bf16* Bb = Bw + bn0 * K;

    int srow = wave * 32 + (lane >> 3);
    int scol = ((lane & 7) ^ (lane >> 3)) << 3;
    int sdst = (wave * 32 + (lane >> 3)) * BK + ((lane & 7) << 3);

    floatx4 acc[4][4] = {};

    for (int k0 = 0; k0 < K; k0 += BK) {
        #pragma unroll
        for (int i = 0; i < 4; ++i) {
            const bf16* ga = Ab + (long)(srow + i * 8) * K + k0 + scol;
            const bf16* gb = Bb + (long)(srow + i * 8) * K + k0 + scol;
            __builtin_amdgcn_global_load_lds((AS1 const unsigned int*)ga,
                                             (AS3 unsigned int*)(Als + sdst + i * 512), 16, 0, 0);
            __builtin_amdgcn_global_load_lds((AS1 const unsigned int*)gb,
                                             (AS3 unsigned int*)(Bls + sdst + i * 512), 16, 0, 0);
        }
        __syncthreads();
        #pragma unroll
        for (int ks = 0; ks < 2; ++ks) {
            bf16x8 af[4], bfr[4];
            #pragma unroll
            for (int t = 0; t < 4; ++t) {
                int row = wm + t * 16 + l16;
                int g = (ks * 4 + quad) ^ (row & 7);
                af[t] = *(const bf16x8*)(Als + row * BK + (g << 3));
            }
            #pragma unroll
            for (int t = 0; t < 4; ++t) {
                int row = wn + t * 16 + l16;
                int g = (ks * 4 + quad) ^ (row & 7);
                bfr[t] = *(const bf16x8*)(Bls + row * BK + (g << 3));
            }
            #pragma unroll
            for (int mt = 0; mt < 4; ++mt)
                #pragma unroll
                for (int nt = 0; nt < 4; ++nt)
                    acc[mt][nt] = __builtin_amdgcn_mfma_f32_16x16x32_bf16(af[mt], bfr[nt], acc[mt][nt], 0, 0, 0);
        }
        __syncthreads();
    }
    #pragma unroll
    for (int mt = 0; mt < 4; ++mt) {
        #pragma unroll
        for (int nt = 0; nt < 4; ++nt) {
            long row = bm0 + wm + mt * 16 + quad * 4;
            long col = bn0 + wn + nt * 16 + l16;
            #pragma unroll
            for (int r = 0; r < 4; ++r)
                C[(row + r) * N + col] = (CT)acc[mt][nt][r];
        }
    }
}

// ---------------------------------------------------------------- canon_b + RMSNorm + RoPE (token-streaming)
// One wave = 512 contiguous channels (16B/lane coalesced) x 8-token chunk
// (+3-token register halo). Rolling conv window in registers; per-head RMS
// via 16-lane shfl reduce (head == 16 lanes); RoPE partner via shfl_xor(8).
// No LDS, no barriers. Sequential tokens per wave -> frag-linear 64B lines
// fill inside one L2 (kills the partial-line write amplification).
__global__ __launch_bounds__(256, 4) void canon_kernel(const bf16* __restrict__ QKV,
                                                       const float* __restrict__ wq,
                                                       const float* __restrict__ wk,
                                                       const float* __restrict__ wv,
                                                       const float* __restrict__ qnw,
                                                       const float* __restrict__ knw,
                                                       const float* __restrict__ cost,
                                                       const float* __restrict__ sint,
                                                       bf16* __restrict__ qf,
                                                       bf16* __restrict__ kf,
                                                       bf16* __restrict__ vf) {
    int tid  = threadIdx.x;
    int wid  = blockIdx.x * 4 + (tid >> 6);
    int lane = tid & 63;
    int b  = wid >> 11;              // 2048 waves per batch
    int g  = (wid >> 8) & 7;         // 512-channel group (0-3 q, 4-5 k, 6-7 v)
    int c  = wid & 255;              // 8-token chunk
    int t0 = c << 3;
    int ch = (g << 9) + (lane << 3); // column in QKV row

    const float* wrow; int cw;
    if (g < 4)      { wrow = wq; cw = ch; }
    else if (g < 6) { wrow = wk; cw = ch - 2048; }
    else            { wrow = wv; cw = ch - 3072; }

    float4 w4[8];                    // w4[i] = {w0,w1,w2,w3} of channel ch+i
    #pragma unroll
    for (int j = 0; j < 8; ++j) w4[j] = *(const float4*)(wrow + (cw + j) * 4);

    union U8 { float4 v; bf16 h[8]; };
    const bf16* srcb = QKV + (size_t)((b << 11) + t0) * 4096 + ch;

    // conv window x[t-1], x[t-2], x[t-3]
    float xm1[8], xm2[8], xm3[8];
    if (t0 > 0) {
        U8 u1, u2, u3;
        u1.v = *(const float4*)(srcb - 4096);
        u2.v = *(const float4*)(srcb - 2 * 4096);
        u3.v = *(const float4*)(srcb - 3 * 4096);
        #pragma unroll
        for (int i = 0; i < 8; ++i) {
            xm1[i] = (float)u1.h[i]; xm2[i] = (float)u2.h[i]; xm3[i] = (float)u3.h[i];
        }
    } else {
        #pragma unroll
        for (int i = 0; i < 8; ++i) { xm1[i] = 0.f; xm2[i] = 0.f; xm3[i] = 0.f; }
    }

    float4 nxtv = *(const float4*)(srcb);   // 1-deep token prefetch

    if (g < 6) {
        // ---------------- Q / K: conv + RMSNorm + RoPE -> frag-linear
        int j0   = ch & 127;                                 // d-offset within head
        int head = (g < 4) ? (ch >> 7) : ((ch - 2048) >> 7);
        const float* nw = (g < 4) ? qnw : knw;
        float nwv[8];
        {
            float4 na = *(const float4*)(nw + j0);
            float4 nb = *(const float4*)(nw + j0 + 4);
            #pragma unroll
            for (int i = 0; i < 8; ++i) nwv[i] = (i < 4) ? (&na.x)[i] : (&nb.x)[i - 4];
        }
        int ks = (lane >> 2) & 3, qd = lane & 3;             // frag coords from j0
        size_t qkbase = ((size_t)((g < 4 ? (b << 4) : (b << 3)) + head) << 18)
                      + ((size_t)(t0 >> 4) << 11) + ((size_t)ks << 9)
                      + ((size_t)qd << 7) + ((size_t)(t0 & 15) << 3);
        bf16* dstb = (g < 4 ? qf : kf) + qkbase;

        int fi0 = j0 & 63;
        bool neg = (j0 < 64);
        const float* ctp = cost + t0 * 64 + fi0;
        const float* stp = sint + t0 * 64 + fi0;

        #pragma unroll
        for (int tt = 0; tt < 8; ++tt) {
            U8 u; u.v = nxtv;
            if (tt < 7) nxtv = *(const float4*)(srcb + (size_t)(tt + 1) * 4096);
            float cur[8], cv[8];
            #pragma unroll
            for (int i = 0; i < 8; ++i) cur[i] = (float)u.h[i];
            #pragma unroll
            for (int i = 0; i < 8; ++i) {
                float a = fmaf(w4[i].x, cur[i], cur[i]);      // x + w0*x[t]
                a = fmaf(w4[i].y, xm1[i], a);
                a = fmaf(w4[i].z, xm2[i], a);
                cv[i] = fmaf(w4[i].w, xm3[i], a);
                xm3[i] = xm2[i]; xm2[i] = xm1[i]; xm1[i] = cur[i];
            }
            // per-head RMS over 16 lanes (128 ch)
            float ss = 0.f;
            #pragma unroll
            for (int i = 0; i < 8; ++i) ss = fmaf(cv[i], cv[i], ss);
            ss += __shfl_xor(ss, 1); ss += __shfl_xor(ss, 2);
            ss += __shfl_xor(ss, 4); ss += __shfl_xor(ss, 8);
            float r1 = rsqrtf(ss * (1.0f / 128.0f) + 1e-6f);
            float xn[8];
            #pragma unroll
            for (int i = 0; i < 8; ++i) xn[i] = cv[i] * r1 * nwv[i];
            // RoPE
            float4 ca = *(const float4*)(ctp + tt * 64);
            float4 cb = *(const float4*)(ctp + tt * 64 + 4);
            float4 sa = *(const float4*)(stp + tt * 64);
            float4 sb = *(const float4*)(stp + tt * 64 + 4);
            __align__(16) bf16 outv[8];
            #pragma unroll
            for (int i = 0; i < 8; ++i) {
                float xp  = __shfl_xor(xn[i], 8);            // partner channel j +/- 64
                float rot = neg ? -xp : xp;
                float cc = (i < 4) ? (&ca.x)[i] : (&cb.x)[i - 4];
                float sn = (i < 4) ? (&sa.x)[i] : (&sb.x)[i - 4];
                outv[i] = (bf16)fmaf(xn[i], cc, rot * sn);
            }
            *(float4*)(dstb + (tt << 3)) = *(const float4*)outv;
        }
    } else {
        // ---------------- V: conv only -> row-major
        int vch  = ch - 3072;
        int head = vch >> 7;
        size_t vbase = ((((size_t)((b << 3) + head) << 11) + (size_t)t0) << 7) + (vch & 127);
        bf16* dstb = vf + vbase;
        #pragma unroll
        for (int tt = 0; tt < 8; ++tt) {
            U8 u; u.v = nxtv;
            if (tt < 7) nxtv = *(const float4*)(srcb + (size_t)(tt + 1) * 4096);
            float cur[8];
            __align__(16) bf16 outv[8];
            #pragma unroll
            for (int i = 0; i < 8; ++i) cur[i] = (float)u.h[i];
            #pragma unroll
            for (int i = 0; i < 8; ++i) {
                float a = fmaf(w4[i].x, cur[i], cur[i]);
                a = fmaf(w4[i].y, xm1[i], a);
                a = fmaf(w4[i].z, xm2[i], a);
                a = fmaf(w4[i].w, xm3[i], a);
                xm3[i] = xm2[i]; xm2[i] = xm1[i]; xm1[i] = cur[i];
                outv[i] = (bf16)a;
            }
            *(float4*)(dstb + tt * 128) = *(const float4*)outv;
        }
    }
}

// ---------------------------------------------------------------- V repack: row-major -> frag-linear
// vf[bk][S][128] -> vfrag[bk][S/64 ktile][ks:2][dnt:8][lane:64][8]
//   element (t,d): kt=t>>6, tt=t&63, ks=tt>>5, quad=(tt>>3)&3, j=tt&7, lane=quad*16+(d&15)
__global__ __launch_bounds__(256) void repack_v(const bf16* __restrict__ vf,
                                                bf16* __restrict__ vfrag) {
    __shared__ __align__(16) bf16 tile[64 * 136];  // [t][d], stride 136
    int kt = blockIdx.x, bk = blockIdx.y;
    int tid = threadIdx.x;
    const bf16* src = vf + (((size_t)bk * S_ + (kt << 6)) << 7);
    #pragma unroll
    for (int p = 0; p < 4; ++p) {
        int c = tid + p * 256;                 // 1024 chunks of 8
        int tt = c >> 4, d0 = (c & 15) << 3;
        *(float4*)(&tile[tt * 136 + d0]) = *(const float4*)(src + ((size_t)tt << 7) + d0);
    }
    __syncthreads();
    bf16* dst = vfrag + (((size_t)bk * 32 + kt) << 13);   // 16 frags * 512
    #pragma unroll
    for (int p = 0; p < 4; ++p) {
        int c = tid + p * 256;                 // frag-chunk id: ks*8*64 + dnt*64 + lane
        int ks = c >> 9, rem = c & 511;
        int dnt = rem >> 6, lane = rem & 63;
        int quad = lane >> 4, l16 = lane & 15;
        __align__(16) bf16 outv[8];
        #pragma unroll
        for (int j = 0; j < 8; ++j)
            outv[j] = tile[(ks * 32 + quad * 8 + j) * 136 + dnt * 16 + l16];
        *(float4*)(dst + ((size_t)c << 3)) = *(float4*)outv;
    }
}

// ---------------------------------------------------------------- flash attention (causal, GQA)
// Frag-linear inputs: every load is base + lane*16B (fully coalesced 1KB).
// Barrier-free, shuffle-free (RMSNorm bounds |s|*log2e <= 16.3 -> no max needed).
__global__ __launch_bounds__(256) void flash_attn(const bf16* __restrict__ qf,
                                                  const bf16* __restrict__ kf,
                                                  const bf16* __restrict__ vfrag,
                                                  bf16* __restrict__ attn) {
    __shared__ __align__(16) bf16 Pls[4][16][72];
    int lid  = blockIdx.x;                         // 0..1023
    int pair = lid & 15;                           // (b*8+kvh) -> stable XCD via lid%8
    int b    = pair >> 3, kvh = pair & 7;
    int inner = lid >> 4;                          // 0..63
    int qt   = 31 - (inner >> 1);                  // longest q-tiles first
    int h    = kvh * 2 + (inner & 1);
    int tid = threadIdx.x, wave = tid >> 6, lane = tid & 63;
    int quad = lane >> 4, l16 = lane & 15;
    int qrow0 = (qt << 6) + (wave << 4);

    const bf16* kfp = kf    + (((size_t)b * KVH_ + kvh) << 18);   // 32 kt * 8192
    const bf16* vfp = vfrag + (((size_t)b * KVH_ + kvh) << 18);
    const bf16* qfp = qf    + ((((size_t)(b * H_ + h) * 128 + (qt << 2) + wave)) << 11);

    bf16x8 aq[4];
    #pragma unroll
    for (int ks = 0; ks < 4; ++ks)
        aq[ks] = *(const bf16x8*)(qfp + (ks << 9) + (lane << 3));

    floatx4 o[8] = {};
    float l_i[4] = {0.f, 0.f, 0.f, 0.f};
    const float scl2 = 0.08838834764831845f * 1.4426950408889634f;  // scale*log2(e)

    int ktiles = qt + 1;
    for (int kt = 0; kt < ktiles; ++kt) {
        int kb = kt << 6;
        const bf16* ktk = kfp + ((size_t)kt << 13);
        const bf16* ktv = vfp + ((size_t)kt << 13);
        // S = Q K^T  (each frag load: lane-contiguous 1KB)
        floatx4 sc[4] = {};
        #pragma unroll
        for (int nt = 0; nt < 4; ++nt) {
            #pragma unroll
            for (int ks = 0; ks < 4; ++ks) {
                bf16x8 kb8 = *(const bf16x8*)(ktk + ((nt * 4 + ks) << 9) + (lane << 3));
                sc[nt] = __builtin_amdgcn_mfma_f32_16x16x32_bf16(aq[ks], kb8, sc[nt], 0, 0, 0);
            }
        }
        // prefetch V ks=0 frags (independent of softmax)
        bf16x8 vpre[8];
        #pragma unroll
        for (int dnt = 0; dnt < 8; ++dnt)
            vpre[dnt] = *(const bf16x8*)(ktv + ((size_t)dnt << 9) + (lane << 3));
        // p = exp2(s*scl2) masked; per-lane l; no cross-lane ops
        int qr0 = qrow0 + (quad << 2);
        #pragma unroll
        for (int nt = 0; nt < 4; ++nt) {
            int key = kb + nt * 16 + l16;
            #pragma unroll
            for (int r = 0; r < 4; ++r) {
                float pv = exp2f(sc[nt][r] * scl2);
                pv = (key <= qr0 + r) ? pv : 0.f;
                l_i[r] += pv;
                Pls[wave][(quad << 2) + r][nt * 16 + l16] = (bf16)pv;
            }
        }
        // O += P V
        {
            bf16x8 pa = *(const bf16x8*)(&Pls[wave][l16][(quad << 3)]);
            #pragma unroll
            for (int dnt = 0; dnt < 8; ++dnt)
                o[dnt] = __builtin_amdgcn_mfma_f32_16x16x32_bf16(pa, vpre[dnt], o[dnt], 0, 0, 0);
            bf16x8 pb = *(const bf16x8*)(&Pls[wave][l16][32 + (quad << 3)]);
            #pragma unroll
            for (int dnt = 0; dnt < 8; ++dnt) {
                bf16x8 vb = *(const bf16x8*)(ktv + ((size_t)(8 + dnt) << 9) + (lane << 3));
                o[dnt] = __builtin_amdgcn_mfma_f32_16x16x32_bf16(pb, vb, o[dnt], 0, 0, 0);
            }
        }
    }
    // epilogue
    #pragma unroll
    for (int r = 0; r < 4; ++r) {
        float l = l_i[r];
        l += __shfl_xor(l, 1); l += __shfl_xor(l, 2);
        l += __shfl_xor(l, 4); l += __shfl_xor(l, 8);
        l_i[r] = 1.0f / l;
    }
    #pragma unroll
    for (int dnt = 0; dnt < 8; ++dnt) {
        #pragma unroll
        for (int r = 0; r < 4; ++r) {
            size_t row = (size_t)b * S_ + qrow0 + (quad << 2) + r;
            attn[row * D_ + h * DH_ + dnt * 16 + l16] = (bf16)(o[dnt][r] * l_i[r]);
        }
    }
}

// ---------------------------------------------------------------- launch
extern "C" void kernel_launch(void* const* d_in, const int* in_sizes, int n_in,
                              void* d_out, int out_size, void* d_ws, size_t ws_size,
                              hipStream_t stream) {
    const float* hidden = (const float*)d_in[0];
    const float* Wq  = (const float*)d_in[1];
    const float* Wk  = (const float*)d_in[2];
    const float* Wv  = (const float*)d_in[3];
    const float* Wo  = (const float*)d_in[4];
    const float* cqw = (const float*)d_in[5];
    const float* ckw = (const float*)d_in[6];
    const float* cvw = (const float*)d_in[7];
    const float* qnw = (const float*)d_in[8];
    const float* knw = (const float*)d_in[9];

    char* p = (char*)d_ws;
    auto alloc = [&](size_t bytes) { char* r = p; p += (bytes + 255) & ~(size_t)255; return r; };
    bf16*  X    = (bf16*)alloc((size_t)M_ * D_ * 2);
    bf16*  Wcat = (bf16*)alloc((size_t)NQKV_ * D_ * 2);
    bf16*  Wob  = (bf16*)alloc((size_t)D_ * D_ * 2);
    bf16*  QKV  = (bf16*)alloc((size_t)M_ * NQKV_ * 2);
    bf16*  qfb  = (bf16*)alloc((size_t)B_ * H_ * S_ * DH_ * 2);   // frag-linear Q
    bf16*  kfb  = (bf16*)alloc((size_t)B_ * KVH_ * S_ * DH_ * 2); // frag-linear K
    bf16*  vfb  = (bf16*)alloc((size_t)B_ * KVH_ * S_ * DH_ * 2); // row-major V
    bf16*  vfr  = (bf16*)alloc((size_t)B_ * KVH_ * S_ * DH_ * 2); // frag-linear V
    float* cost = (float*)alloc((size_t)S_ * 64 * 4);
    float* sint = (float*)alloc((size_t)S_ * 64 * 4);
    bf16*  attnb = QKV;   // QKV dead after canon_kernel

    cast_kernel<<<M_ * D_ / 4 / 256, 256, 0, stream>>>(hidden, X, M_ * D_);
    cast_kernel<<<D_ * D_ / 4 / 256, 256, 0, stream>>>(Wq, Wcat, D_ * D_);
    cast_kernel<<<1024 * 2048 / 4 / 256, 256, 0, stream>>>(Wk, Wcat + (size_t)2048 * 2048, 1024 * 2048);
    cast_kernel<<<1024 * 2048 / 4 / 256, 256, 0, stream>>>(Wv, Wcat + (size_t)3072 * 2048, 1024 * 2048);
    cast_kernel<<<D_ * D_ / 4 / 256, 256, 0, stream>>>(Wo, Wob, D_ * D_);
    rope_table<<<S_ * 64 / 256, 256, 0, stream>>>(cost, sint);

    gemm_bt<bf16><<<dim3(NQKV_ / BN, M_ / BM), 256, 0, stream>>>(X, Wcat, QKV, M_, NQKV_, D_);
    canon_kernel<<<1024, 256, 0, stream>>>(QKV, cqw, ckw, cvw, qnw, knw, cost, sint, qfb, kfb, vfb);
    repack_v<<<dim3(S_ / 64, B_ * KVH_), 256, 0, stream>>>(vfb, vfr);
    flash_attn<<<1024, 256, 0, stream>>>(qfb, kfb, vfr, attnb);
    gemm_bt<float><<<dim3(D_ / BN, M_ / BM), 256, 0, stream>>>(attnb, Wob, (float*)d_out, M_, D_, D_);
}

// Round 4
// 486.151 us; speedup vs baseline: 1.2862x; 1.0922x over previous
//
#include <hip/hip_runtime.h>
#include <hip/hip_bf16.h>

typedef __bf16 bf16;
typedef __bf16 bf16x8 __attribute__((ext_vector_type(8)));
typedef float  floatx4 __attribute__((ext_vector_type(4)));

#define AS1 __attribute__((address_space(1)))
#define AS3 __attribute__((address_space(3)))

#define B_    2
#define S_    2048
#define D_    2048
#define H_    16
#define KVH_  8
#define DH_   128
#define M_    4096      // B_*S_
#define NQKV_ 4096      // D_ + 2*KVH_*DH_

// ---------------------------------------------------------------- cast fp32 -> bf16
__global__ __launch_bounds__(256) void cast_kernel(const float* __restrict__ in,
                                                   bf16* __restrict__ out, int n) {
    int i = (blockIdx.x * blockDim.x + threadIdx.x) * 4;
    if (i < n) {
        float4 v = *(const float4*)(in + i);
        union { bf16 h[4]; double d; } u;
        u.h[0] = (bf16)v.x; u.h[1] = (bf16)v.y; u.h[2] = (bf16)v.z; u.h[3] = (bf16)v.w;
        *(double*)(out + i) = u.d;
    }
}

// ---------------------------------------------------------------- RoPE tables [S][64]
__global__ __launch_bounds__(256) void rope_table(float* __restrict__ cost,
                                                  float* __restrict__ sint) {
    int i = blockIdx.x * blockDim.x + threadIdx.x;   // S_*64 threads
    int t = i >> 6, fi = i & 63;
    float inv = expf(-9.210340371976184f * (float)fi * (1.0f / 64.0f)); // 10000^(-fi/64)
    float ang = (float)t * inv;
    cost[i] = cosf(ang);
    sint[i] = sinf(ang);
}

// ---------------------------------------------------------------- GEMM: C[M,N] = A[M,K] * B[N,K]^T   (bf16 in, fp32 acc, CT out)
#define BM 128
#define BN 128
#define BK 64
template <typename CT>
__global__ __launch_bounds__(256) void gemm_bt(const bf16* __restrict__ A,
                                               const bf16* __restrict__ Bw,
                                               CT* __restrict__ C,
                                               int M, int N, int K) {
    __shared__ __align__(16) bf16 Als[BM * BK];
    __shared__ __align__(16) bf16 Bls[BN * BK];
    int tid  = threadIdx.x;
    int wave = tid >> 6, lane = tid & 63;
    int quad = lane >> 4, l16 = lane & 15;
    int wm = (wave >> 1) << 6;   // 0 / 64
    int wn = (wave & 1) << 6;

    long bm0 = (long)blockIdx.y * BM;
    long bn0 = (long)blockIdx.x * BN;
    const bf16* Ab = A  + bm0 * K;
    const bf16* Bb = Bw + bn0 * K;

    int srow = wave * 32 + (lane >> 3);
    int scol = ((lane & 7) ^ (lane >> 3)) << 3;
    int sdst = (wave * 32 + (lane >> 3)) * BK + ((lane & 7) << 3);

    floatx4 acc[4][4] = {};

    for (int k0 = 0; k0 < K; k0 += BK) {
        #pragma unroll
        for (int i = 0; i < 4; ++i) {
            const bf16* ga = Ab + (long)(srow + i * 8) * K + k0 + scol;
            const bf16* gb = Bb + (long)(srow + i * 8) * K + k0 + scol;
            __builtin_amdgcn_global_load_lds((AS1 const unsigned int*)ga,
                                             (AS3 unsigned int*)(Als + sdst + i * 512), 16, 0, 0);
            __builtin_amdgcn_global_load_lds((AS1 const unsigned int*)gb,
                                             (AS3 unsigned int*)(Bls + sdst + i * 512), 16, 0, 0);
        }
        __syncthreads();
        #pragma unroll
        for (int ks = 0; ks < 2; ++ks) {
            bf16x8 af[4], bfr[4];
            #pragma unroll
            for (int t = 0; t < 4; ++t) {
                int row = wm + t * 16 + l16;
                int g = (ks * 4 + quad) ^ (row & 7);
                af[t] = *(const bf16x8*)(Als + row * BK + (g << 3));
            }
            #pragma unroll
            for (int t = 0; t < 4; ++t) {
                int row = wn + t * 16 + l16;
                int g = (ks * 4 + quad) ^ (row & 7);
                bfr[t] = *(const bf16x8*)(Bls + row * BK + (g << 3));
            }
            #pragma unroll
            for (int mt = 0; mt < 4; ++mt)
                #pragma unroll
                for (int nt = 0; nt < 4; ++nt)
                    acc[mt][nt] = __builtin_amdgcn_mfma_f32_16x16x32_bf16(af[mt], bfr[nt], acc[mt][nt], 0, 0, 0);
        }
        __syncthreads();
    }
    #pragma unroll
    for (int mt = 0; mt < 4; ++mt) {
        #pragma unroll
        for (int nt = 0; nt < 4; ++nt) {
            long row = bm0 + wm + mt * 16 + quad * 4;
            long col = bn0 + wn + nt * 16 + l16;
            #pragma unroll
            for (int r = 0; r < 4; ++r)
                C[(row + r) * N + col] = (CT)acc[mt][nt][r];
        }
    }
}

// ---------------------------------------------------------------- canon_b + RMSNorm + RoPE (token-streaming)
// One wave = 512 contiguous channels (16B/lane coalesced) x 8-token chunk
// (+3-token register halo). Rolling conv window in registers; per-head RMS
// via 16-lane shfl reduce (head == 16 lanes); RoPE partner via shfl_xor(8).
// No LDS, no barriers.
__global__ __launch_bounds__(256, 4) void canon_kernel(const bf16* __restrict__ QKV,
                                                       const float* __restrict__ wq,
                                                       const float* __restrict__ wk,
                                                       const float* __restrict__ wv,
                                                       const float* __restrict__ qnw,
                                                       const float* __restrict__ knw,
                                                       const float* __restrict__ cost,
                                                       const float* __restrict__ sint,
                                                       bf16* __restrict__ qf,
                                                       bf16* __restrict__ kf,
                                                       bf16* __restrict__ vf) {
    int tid  = threadIdx.x;
    int wid  = blockIdx.x * 4 + (tid >> 6);
    int lane = tid & 63;
    int b  = wid >> 11;              // 2048 waves per batch
    int g  = (wid >> 8) & 7;         // 512-channel group (0-3 q, 4-5 k, 6-7 v)
    int c  = wid & 255;              // 8-token chunk
    int t0 = c << 3;
    int ch = (g << 9) + (lane << 3); // column in QKV row

    const float* wrow; int cw;
    if (g < 4)      { wrow = wq; cw = ch; }
    else if (g < 6) { wrow = wk; cw = ch - 2048; }
    else            { wrow = wv; cw = ch - 3072; }

    float4 w4[8];                    // w4[i] = {w0,w1,w2,w3} of channel ch+i
    #pragma unroll
    for (int j = 0; j < 8; ++j) w4[j] = *(const float4*)(wrow + (cw + j) * 4);

    union U8 { float4 v; bf16 h[8]; };
    const bf16* srcb = QKV + (size_t)((b << 11) + t0) * 4096 + ch;

    // conv window x[t-1], x[t-2], x[t-3]
    float xm1[8], xm2[8], xm3[8];
    if (t0 > 0) {
        U8 u1, u2, u3;
        u1.v = *(const float4*)(srcb - 4096);
        u2.v = *(const float4*)(srcb - 2 * 4096);
        u3.v = *(const float4*)(srcb - 3 * 4096);
        #pragma unroll
        for (int i = 0; i < 8; ++i) {
            xm1[i] = (float)u1.h[i]; xm2[i] = (float)u2.h[i]; xm3[i] = (float)u3.h[i];
        }
    } else {
        #pragma unroll
        for (int i = 0; i < 8; ++i) { xm1[i] = 0.f; xm2[i] = 0.f; xm3[i] = 0.f; }
    }

    float4 nxtv = *(const float4*)(srcb);   // 1-deep token prefetch

    if (g < 6) {
        // ---------------- Q / K: conv + RMSNorm + RoPE -> frag-linear
        int j0   = ch & 127;                                 // d-offset within head
        int head = (g < 4) ? (ch >> 7) : ((ch - 2048) >> 7);
        const float* nw = (g < 4) ? qnw : knw;
        float nwv[8];
        {
            float4 na = *(const float4*)(nw + j0);
            float4 nb = *(const float4*)(nw + j0 + 4);
            #pragma unroll
            for (int i = 0; i < 8; ++i) nwv[i] = (i < 4) ? (&na.x)[i] : (&nb.x)[i - 4];
        }
        int ks = (lane >> 2) & 3, qd = lane & 3;             // frag coords from j0
        size_t qkbase = ((size_t)((g < 4 ? (b << 4) : (b << 3)) + head) << 18)
                      + ((size_t)(t0 >> 4) << 11) + ((size_t)ks << 9)
                      + ((size_t)qd << 7) + ((size_t)(t0 & 15) << 3);
        bf16* dstb = (g < 4 ? qf : kf) + qkbase;

        int fi0 = j0 & 63;
        bool neg = (j0 < 64);
        const float* ctp = cost + t0 * 64 + fi0;
        const float* stp = sint + t0 * 64 + fi0;

        #pragma unroll
        for (int tt = 0; tt < 8; ++tt) {
            U8 u; u.v = nxtv;
            if (tt < 7) nxtv = *(const float4*)(srcb + (size_t)(tt + 1) * 4096);
            float cur[8], cv[8];
            #pragma unroll
            for (int i = 0; i < 8; ++i) cur[i] = (float)u.h[i];
            #pragma unroll
            for (int i = 0; i < 8; ++i) {
                float a = fmaf(w4[i].x, cur[i], cur[i]);      // x + w0*x[t]
                a = fmaf(w4[i].y, xm1[i], a);
                a = fmaf(w4[i].z, xm2[i], a);
                cv[i] = fmaf(w4[i].w, xm3[i], a);
                xm3[i] = xm2[i]; xm2[i] = xm1[i]; xm1[i] = cur[i];
            }
            // per-head RMS over 16 lanes (128 ch)
            float ss = 0.f;
            #pragma unroll
            for (int i = 0; i < 8; ++i) ss = fmaf(cv[i], cv[i], ss);
            ss += __shfl_xor(ss, 1); ss += __shfl_xor(ss, 2);
            ss += __shfl_xor(ss, 4); ss += __shfl_xor(ss, 8);
            float r1 = rsqrtf(ss * (1.0f / 128.0f) + 1e-6f);
            float xn[8];
            #pragma unroll
            for (int i = 0; i < 8; ++i) xn[i] = cv[i] * r1 * nwv[i];
            // RoPE
            float4 ca = *(const float4*)(ctp + tt * 64);
            float4 cb = *(const float4*)(ctp + tt * 64 + 4);
            float4 sa = *(const float4*)(stp + tt * 64);
            float4 sb = *(const float4*)(stp + tt * 64 + 4);
            __align__(16) bf16 outv[8];
            #pragma unroll
            for (int i = 0; i < 8; ++i) {
                float xp  = __shfl_xor(xn[i], 8);            // partner channel j +/- 64
                float rot = neg ? -xp : xp;
                float cc = (i < 4) ? (&ca.x)[i] : (&cb.x)[i - 4];
                float sn = (i < 4) ? (&sa.x)[i] : (&sb.x)[i - 4];
                outv[i] = (bf16)fmaf(xn[i], cc, rot * sn);
            }
            *(float4*)(dstb + (tt << 3)) = *(const float4*)outv;
        }
    } else {
        // ---------------- V: conv only -> row-major
        int vch  = ch - 3072;
        int head = vch >> 7;
        size_t vbase = ((((size_t)((b << 3) + head) << 11) + (size_t)t0) << 7) + (vch & 127);
        bf16* dstb = vf + vbase;
        #pragma unroll
        for (int tt = 0; tt < 8; ++tt) {
            U8 u; u.v = nxtv;
            if (tt < 7) nxtv = *(const float4*)(srcb + (size_t)(tt + 1) * 4096);
            float cur[8];
            __align__(16) bf16 outv[8];
            #pragma unroll
            for (int i = 0; i < 8; ++i) cur[i] = (float)u.h[i];
            #pragma unroll
            for (int i = 0; i < 8; ++i) {
                float a = fmaf(w4[i].x, cur[i], cur[i]);
                a = fmaf(w4[i].y, xm1[i], a);
                a = fmaf(w4[i].z, xm2[i], a);
                a = fmaf(w4[i].w, xm3[i], a);
                xm3[i] = xm2[i]; xm2[i] = xm1[i]; xm1[i] = cur[i];
                outv[i] = (bf16)a;
            }
            *(float4*)(dstb + tt * 128) = *(const float4*)outv;
        }
    }
}

// ---------------------------------------------------------------- V repack: row-major -> frag-linear
// vf[bk][S][128] -> vfrag[bk][S/64 ktile][ks:2][dnt:8][lane:64][8]
//   element (t,d): kt=t>>6, tt=t&63, ks=tt>>5, quad=(tt>>3)&3, j=tt&7, lane=quad*16+(d&15)
__global__ __launch_bounds__(256) void repack_v(const bf16* __restrict__ vf,
                                                bf16* __restrict__ vfrag) {
    __shared__ __align__(16) bf16 tile[64 * 136];  // [t][d], stride 136
    int kt = blockIdx.x, bk = blockIdx.y;
    int tid = threadIdx.x;
    const bf16* src = vf + (((size_t)bk * S_ + (kt << 6)) << 7);
    #pragma unroll
    for (int p = 0; p < 4; ++p) {
        int c = tid + p * 256;                 // 1024 chunks of 8
        int tt = c >> 4, d0 = (c & 15) << 3;
        *(float4*)(&tile[tt * 136 + d0]) = *(const float4*)(src + ((size_t)tt << 7) + d0);
    }
    __syncthreads();
    bf16* dst = vfrag + (((size_t)bk * 32 + kt) << 13);   // 16 frags * 512
    #pragma unroll
    for (int p = 0; p < 4; ++p) {
        int c = tid + p * 256;                 // frag-chunk id: ks*8*64 + dnt*64 + lane
        int ks = c >> 9, rem = c & 511;
        int dnt = rem >> 6, lane = rem & 63;
        int quad = lane >> 4, l16 = lane & 15;
        __align__(16) bf16 outv[8];
        #pragma unroll
        for (int j = 0; j < 8; ++j)
            outv[j] = tile[(ks * 32 + quad * 8 + j) * 136 + dnt * 16 + l16];
        *(float4*)(dst + ((size_t)c << 3)) = *(float4*)outv;
    }
}

// ---------------------------------------------------------------- flash attention (causal, GQA)
// K/V tiles staged once per block into double-buffered LDS via global_load_lds
// (frag-linear layout == linear stage, lane x 16B), shared by all 4 waves:
// 4x less L2 traffic than per-wave global reads. 2-phase async pipeline:
// barrier -> issue next-tile stage -> compute current (stage overlaps compute,
// one vmcnt-drain barrier per tile). Causal mask peeled to the final tile.
// Stage partition: 256 threads x 16B x 4 passes = 16KB tile; per-thread
// element offset tid*8, pass stride 2048 elems (wave-uniform base + lane*16B).
__global__ __launch_bounds__(256) void flash_attn(const bf16* __restrict__ qf,
                                                  const bf16* __restrict__ kf,
                                                  const bf16* __restrict__ vfrag,
                                                  bf16* __restrict__ attn) {
    __shared__ __align__(16) bf16 Kls[2][8192];   // 64 keys x 128 d, frag-linear
    __shared__ __align__(16) bf16 Vls[2][8192];
    __shared__ __align__(16) bf16 Pls[4][16][72];
    int lid  = blockIdx.x;                         // 0..1023
    int pair = lid & 15;                           // (b*8+kvh) -> stable XCD via lid%8
    int b    = pair >> 3, kvh = pair & 7;
    int inner = lid >> 4;                          // 0..63
    int qt   = 31 - (inner >> 1);                  // longest q-tiles first
    int h    = kvh * 2 + (inner & 1);
    int tid = threadIdx.x, wave = tid >> 6, lane = tid & 63;
    int quad = lane >> 4, l16 = lane & 15;
    int qrow0 = (qt << 6) + (wave << 4);

    const bf16* kfp = kf    + (((size_t)b * KVH_ + kvh) << 18);   // 32 kt * 8192
    const bf16* vfp = vfrag + (((size_t)b * KVH_ + kvh) << 18);
    const bf16* qfp = qf    + ((((size_t)(b * H_ + h) * 128 + (qt << 2) + wave)) << 11);

    bf16x8 aq[4];
    #pragma unroll
    for (int ks = 0; ks < 4; ++ks)
        aq[ks] = *(const bf16x8*)(qfp + (ks << 9) + (lane << 3));

    floatx4 o[8] = {};
    float l_i[4] = {0.f, 0.f, 0.f, 0.f};
    const float scl2 = 0.08838834764831845f * 1.4426950408889634f;  // scale*log2(e)

    int ktiles = qt + 1;
    int eo = tid << 3;                 // stage offset: tid*8 elems (lane*16B within wave)

    // prologue: issue stage of tile 0 into buf 0
    #pragma unroll
    for (int i = 0; i < 4; ++i) {
        __builtin_amdgcn_global_load_lds((AS1 const unsigned int*)(kfp + eo + (i << 11)),
                                         (AS3 unsigned int*)(&Kls[0][0] + eo + (i << 11)), 16, 0, 0);
        __builtin_amdgcn_global_load_lds((AS1 const unsigned int*)(vfp + eo + (i << 11)),
                                         (AS3 unsigned int*)(&Vls[0][0] + eo + (i << 11)), 16, 0, 0);
    }

    int cur = 0;
    for (int kt = 0; kt < ktiles; ++kt) {
        __syncthreads();   // drains the stage of buf[cur]; fences prev compute on buf[cur^1]
        if (kt + 1 < ktiles) {
            const bf16* ksrc = kfp + (((size_t)(kt + 1)) << 13) + eo;
            const bf16* vsrc = vfp + (((size_t)(kt + 1)) << 13) + eo;
            bf16* kd = &Kls[cur ^ 1][0] + eo;
            bf16* vd = &Vls[cur ^ 1][0] + eo;
            #pragma unroll
            for (int i = 0; i < 4; ++i) {
                __builtin_amdgcn_global_load_lds((AS1 const unsigned int*)(ksrc + (i << 11)),
                                                 (AS3 unsigned int*)(kd + (i << 11)), 16, 0, 0);
                __builtin_amdgcn_global_load_lds((AS1 const unsigned int*)(vsrc + (i << 11)),
                                                 (AS3 unsigned int*)(vd + (i << 11)), 16, 0, 0);
            }
        }
        const bf16* Kb = &Kls[cur][0];
        const bf16* Vb = &Vls[cur][0];
        // S = Q K^T (K frags from LDS: contiguous 1KB per frag, conflict-free)
        floatx4 sc[4] = {};
        #pragma unroll
        for (int nt = 0; nt < 4; ++nt) {
            #pragma unroll
            for (int ks = 0; ks < 4; ++ks) {
                bf16x8 kb8 = *(const bf16x8*)(Kb + ((nt * 4 + ks) << 9) + (lane << 3));
                sc[nt] = __builtin_amdgcn_mfma_f32_16x16x32_bf16(aq[ks], kb8, sc[nt], 0, 0, 0);
            }
        }
        // p = exp2(s*scl2); mask only on the final (diagonal) tile
        int qr0 = qrow0 + (quad << 2);
        int kb = kt << 6;
        if (kt == ktiles - 1) {
            #pragma unroll
            for (int nt = 0; nt < 4; ++nt) {
                int key = kb + nt * 16 + l16;
                #pragma unroll
                for (int r = 0; r < 4; ++r) {
                    float pv = exp2f(sc[nt][r] * scl2);
                    pv = (key <= qr0 + r) ? pv : 0.f;
                    l_i[r] += pv;
                    Pls[wave][(quad << 2) + r][nt * 16 + l16] = (bf16)pv;
                }
            }
        } else {
            #pragma unroll
            for (int nt = 0; nt < 4; ++nt) {
                #pragma unroll
                for (int r = 0; r < 4; ++r) {
                    float pv = exp2f(sc[nt][r] * scl2);
                    l_i[r] += pv;
                    Pls[wave][(quad << 2) + r][nt * 16 + l16] = (bf16)pv;
                }
            }
        }
        // O += P V (V frags from LDS)
        {
            bf16x8 pa = *(const bf16x8*)(&Pls[wave][l16][(quad << 3)]);
            #pragma unroll
            for (int dnt = 0; dnt < 8; ++dnt) {
                bf16x8 vb = *(const bf16x8*)(Vb + ((size_t)dnt << 9) + (lane << 3));
                o[dnt] = __builtin_amdgcn_mfma_f32_16x16x32_bf16(pa, vb, o[dnt], 0, 0, 0);
            }
            bf16x8 pb = *(const bf16x8*)(&Pls[wave][l16][32 + (quad << 3)]);
            #pragma unroll
            for (int dnt = 0; dnt < 8; ++dnt) {
                bf16x8 vb = *(const bf16x8*)(Vb + ((size_t)(8 + dnt) << 9) + (lane << 3));
                o[dnt] = __builtin_amdgcn_mfma_f32_16x16x32_bf16(pb, vb, o[dnt], 0, 0, 0);
            }
        }
        cur ^= 1;
    }
    // epilogue
    #pragma unroll
    for (int r = 0; r < 4; ++r) {
        float l = l_i[r];
        l += __shfl_xor(l, 1); l += __shfl_xor(l, 2);
        l += __shfl_xor(l, 4); l += __shfl_xor(l, 8);
        l_i[r] = 1.0f / l;
    }
    #pragma unroll
    for (int dnt = 0; dnt < 8; ++dnt) {
        #pragma unroll
        for (int r = 0; r < 4; ++r) {
            size_t row = (size_t)b * S_ + qrow0 + (quad << 2) + r;
            attn[row * D_ + h * DH_ + dnt * 16 + l16] = (bf16)(o[dnt][r] * l_i[r]);
        }
    }
}

// ---------------------------------------------------------------- launch
extern "C" void kernel_launch(void* const* d_in, const int* in_sizes, int n_in,
                              void* d_out, int out_size, void* d_ws, size_t ws_size,
                              hipStream_t stream) {
    const float* hidden = (const float*)d_in[0];
    const float* Wq  = (const float*)d_in[1];
    const float* Wk  = (const float*)d_in[2];
    const float* Wv  = (const float*)d_in[3];
    const float* Wo  = (const float*)d_in[4];
    const float* cqw = (const float*)d_in[5];
    const float* ckw = (const float*)d_in[6];
    const float* cvw = (const float*)d_in[7];
    const float* qnw = (const float*)d_in[8];
    const float* knw = (const float*)d_in[9];

    char* p = (char*)d_ws;
    auto alloc = [&](size_t bytes) { char* r = p; p += (bytes + 255) & ~(size_t)255; return r; };
    bf16*  X    = (bf16*)alloc((size_t)M_ * D_ * 2);
    bf16*  Wcat = (bf16*)alloc((size_t)NQKV_ * D_ * 2);
    bf16*  Wob  = (bf16*)alloc((size_t)D_ * D_ * 2);
    bf16*  QKV  = (bf16*)alloc((size_t)M_ * NQKV_ * 2);
    bf16*  qfb  = (bf16*)alloc((size_t)B_ * H_ * S_ * DH_ * 2);   // frag-linear Q
    bf16*  kfb  = (bf16*)alloc((size_t)B_ * KVH_ * S_ * DH_ * 2); // frag-linear K
    bf16*  vfb  = (bf16*)alloc((size_t)B_ * KVH_ * S_ * DH_ * 2); // row-major V
    bf16*  vfr  = (bf16*)alloc((size_t)B_ * KVH_ * S_ * DH_ * 2); // frag-linear V
    float* cost = (float*)alloc((size_t)S_ * 64 * 4);
    float* sint = (float*)alloc((size_t)S_ * 64 * 4);
    bf16*  attnb = QKV;   // QKV dead after canon_kernel

    cast_kernel<<<M_ * D_ / 4 / 256, 256, 0, stream>>>(hidden, X, M_ * D_);
    cast_kernel<<<D_ * D_ / 4 / 256, 256, 0, stream>>>(Wq, Wcat, D_ * D_);
    cast_kernel<<<1024 * 2048 / 4 / 256, 256, 0, stream>>>(Wk, Wcat + (size_t)2048 * 2048, 1024 * 2048);
    cast_kernel<<<1024 * 2048 / 4 / 256, 256, 0, stream>>>(Wv, Wcat + (size_t)3072 * 2048, 1024 * 2048);
    cast_kernel<<<D_ * D_ / 4 / 256, 256, 0, stream>>>(Wo, Wob, D_ * D_);
    rope_table<<<S_ * 64 / 256, 256, 0, stream>>>(cost, sint);

    gemm_bt<bf16><<<dim3(NQKV_ / BN, M_ / BM), 256, 0, stream>>>(X, Wcat, QKV, M_, NQKV_, D_);
    canon_kernel<<<1024, 256, 0, stream>>>(QKV, cqw, ckw, cvw, qnw, knw, cost, sint, qfb, kfb, vfb);
    repack_v<<<dim3(S_ / 64, B_ * KVH_), 256, 0, stream>>>(vfb, vfr);
    flash_attn<<<1024, 256, 0, stream>>>(qfb, kfb, vfr, attnb);
    gemm_bt<float><<<dim3(D_ / BN, M_ / BM), 256, 0, stream>>>(attnb, Wob, (float*)d_out, M_, D_, D_);
}

// Round 5
// 377.476 us; speedup vs baseline: 1.6564x; 1.2879x over previous
//
#include <hip/hip_runtime.h>
#include <hip/hip_bf16.h>

typedef __bf16 bf16;
typedef __bf16 bf16x8 __attribute__((ext_vector_type(8)));
typedef float  floatx4 __attribute__((ext_vector_type(4)));

#define AS1 __attribute__((address_space(1)))
#define AS3 __attribute__((address_space(3)))

#define B_    2
#define S_    2048
#define D_    2048
#define H_    16
#define KVH_  8
#define DH_   128
#define M_    4096      // B_*S_
#define NQKV_ 4096      // D_ + 2*KVH_*DH_

// ---------------------------------------------------------------- fused prep: all fp32->bf16 casts + RoPE tables
// Region map (4-elem units): X 2097152 | Wq 1048576 | Wk 524288 | Wv 524288 | Wo 1048576
// then rope: 131072 single-elem units. Total threads 5373952 = 20992 blocks x 256.
__global__ __launch_bounds__(256) void prep_kernel(const float* __restrict__ hidden,
                                                   const float* __restrict__ Wq,
                                                   const float* __restrict__ Wk,
                                                   const float* __restrict__ Wv,
                                                   const float* __restrict__ Wo,
                                                   bf16* __restrict__ X,
                                                   bf16* __restrict__ Wcat,
                                                   bf16* __restrict__ Wob,
                                                   float* __restrict__ cost,
                                                   float* __restrict__ sint) {
    size_t u = (size_t)blockIdx.x * 256 + threadIdx.x;
    if (u < 5242880) {
        const float* src; bf16* dst; size_t off;
        if (u < 2097152)      { src = hidden; dst = X;              off = u; }
        else if (u < 3145728) { src = Wq;     dst = Wcat;           off = u - 2097152; }
        else if (u < 3670016) { src = Wk;     dst = Wcat + 4194304; off = u - 3145728; }
        else if (u < 4194304) { src = Wv;     dst = Wcat + 6291456; off = u - 3670016; }
        else                  { src = Wo;     dst = Wob;            off = u - 4194304; }
        float4 v = *(const float4*)(src + off * 4);
        union { bf16 h[4]; double d; } uu;
        uu.h[0] = (bf16)v.x; uu.h[1] = (bf16)v.y; uu.h[2] = (bf16)v.z; uu.h[3] = (bf16)v.w;
        *(double*)(dst + off * 4) = uu.d;
    } else {
        int r = (int)(u - 5242880);              // 0..131071
        int t = r >> 6, fi = r & 63;
        float inv = expf(-9.210340371976184f * (float)fi * (1.0f / 64.0f)); // 10000^(-fi/64)
        float ang = (float)t * inv;
        cost[r] = cosf(ang);
        sint[r] = sinf(ang);
    }
}

// ---------------------------------------------------------------- GEMM: C[M,N] = A[M,K] * B[N,K]^T   (bf16 in, fp32 acc, CT out)
#define BM 128
#define BN 128
#define BK 64
template <typename CT>
__global__ __launch_bounds__(256) void gemm_bt(const bf16* __restrict__ A,
                                               const bf16* __restrict__ Bw,
                                               CT* __restrict__ C,
                                               int M, int N, int K) {
    __shared__ __align__(16) bf16 Als[BM * BK];
    __shared__ __align__(16) bf16 Bls[BN * BK];
    int tid  = threadIdx.x;
    int wave = tid >> 6, lane = tid & 63;
    int quad = lane >> 4, l16 = lane & 15;
    int wm = (wave >> 1) << 6;   // 0 / 64
    int wn = (wave & 1) << 6;

    long bm0 = (long)blockIdx.y * BM;
    long bn0 = (long)blockIdx.x * BN;
    const bf16* Ab = A  + bm0 * K;
    const bf16* Bb = Bw + bn0 * K;

    int srow = wave * 32 + (lane >> 3);
    int scol = ((lane & 7) ^ (lane >> 3)) << 3;
    int sdst = (wave * 32 + (lane >> 3)) * BK + ((lane & 7) << 3);

    floatx4 acc[4][4] = {};

    for (int k0 = 0; k0 < K; k0 += BK) {
        #pragma unroll
        for (int i = 0; i < 4; ++i) {
            const bf16* ga = Ab + (long)(srow + i * 8) * K + k0 + scol;
            const bf16* gb = Bb + (long)(srow + i * 8) * K + k0 + scol;
            __builtin_amdgcn_global_load_lds((AS1 const unsigned int*)ga,
                                             (AS3 unsigned int*)(Als + sdst + i * 512), 16, 0, 0);
            __builtin_amdgcn_global_load_lds((AS1 const unsigned int*)gb,
                                             (AS3 unsigned int*)(Bls + sdst + i * 512), 16, 0, 0);
        }
        __syncthreads();
        #pragma unroll
        for (int ks = 0; ks < 2; ++ks) {
            bf16x8 af[4], bfr[4];
            #pragma unroll
            for (int t = 0; t < 4; ++t) {
                int row = wm + t * 16 + l16;
                int g = (ks * 4 + quad) ^ (row & 7);
                af[t] = *(const bf16x8*)(Als + row * BK + (g << 3));
            }
            #pragma unroll
            for (int t = 0; t < 4; ++t) {
                int row = wn + t * 16 + l16;
                int g = (ks * 4 + quad) ^ (row & 7);
                bfr[t] = *(const bf16x8*)(Bls + row * BK + (g << 3));
            }
            #pragma unroll
            for (int mt = 0; mt < 4; ++mt)
                #pragma unroll
                for (int nt = 0; nt < 4; ++nt)
                    acc[mt][nt] = __builtin_amdgcn_mfma_f32_16x16x32_bf16(af[mt], bfr[nt], acc[mt][nt], 0, 0, 0);
        }
        __syncthreads();
    }
    #pragma unroll
    for (int mt = 0; mt < 4; ++mt) {
        #pragma unroll
        for (int nt = 0; nt < 4; ++nt) {
            long row = bm0 + wm + mt * 16 + quad * 4;
            long col = bn0 + wn + nt * 16 + l16;
            #pragma unroll
            for (int r = 0; r < 4; ++r)
                C[(row + r) * N + col] = (CT)acc[mt][nt][r];
        }
    }
}

// ---------------------------------------------------------------- canon_b + RMSNorm + RoPE (token-streaming) + fused V repack
// One wave = 512 contiguous channels (16B/lane coalesced) x 8-token chunk
// (+3-token register halo). Rolling conv window in registers; per-head RMS
// via 16-lane shfl reduce; RoPE partner via shfl_xor(8). Q/K path: no LDS,
// no barriers. V path: block covers 32 aligned tokens x 512 ch = one (kt,ks)
// frag half-tile for 4 KV heads -> conv into a 32x520 LDS tile (16B-aligned
// rows, conflict-free b128 writes), barrier, gather frag-linear, coalesced
// 16B global writes. Eliminates the separate repack_v kernel + vfb buffer.
__global__ __launch_bounds__(256, 4) void canon_kernel(const bf16* __restrict__ QKV,
                                                       const float* __restrict__ wq,
                                                       const float* __restrict__ wk,
                                                       const float* __restrict__ wv,
                                                       const float* __restrict__ qnw,
                                                       const float* __restrict__ knw,
                                                       const float* __restrict__ cost,
                                                       const float* __restrict__ sint,
                                                       bf16* __restrict__ qf,
                                                       bf16* __restrict__ kf,
                                                       bf16* __restrict__ vfrag) {
    __shared__ __align__(16) bf16 vtile[32 * 520];   // V blocks only; 520 = 16B-aligned pad
    int tid  = threadIdx.x;
    int wid  = blockIdx.x * 4 + (tid >> 6);
    int lane = tid & 63;
    int b  = wid >> 11;              // 2048 waves per batch
    int g  = (wid >> 8) & 7;         // 512-channel group (0-3 q, 4-5 k, 6-7 v); block-uniform
    int c  = wid & 255;              // 8-token chunk
    int t0 = c << 3;
    int ch = (g << 9) + (lane << 3); // column in QKV row

    const float* wrow; int cw;
    if (g < 4)      { wrow = wq; cw = ch; }
    else if (g < 6) { wrow = wk; cw = ch - 2048; }
    else            { wrow = wv; cw = ch - 3072; }

    float4 w4[8];                    // w4[i] = {w0,w1,w2,w3} of channel ch+i
    #pragma unroll
    for (int j = 0; j < 8; ++j) w4[j] = *(const float4*)(wrow + (cw + j) * 4);

    union U8 { float4 v; bf16 h[8]; };
    const bf16* srcb = QKV + (size_t)((b << 11) + t0) * 4096 + ch;

    // conv window x[t-1], x[t-2], x[t-3]
    float xm1[8], xm2[8], xm3[8];
    if (t0 > 0) {
        U8 u1, u2, u3;
        u1.v = *(const float4*)(srcb - 4096);
        u2.v = *(const float4*)(srcb - 2 * 4096);
        u3.v = *(const float4*)(srcb - 3 * 4096);
        #pragma unroll
        for (int i = 0; i < 8; ++i) {
            xm1[i] = (float)u1.h[i]; xm2[i] = (float)u2.h[i]; xm3[i] = (float)u3.h[i];
        }
    } else {
        #pragma unroll
        for (int i = 0; i < 8; ++i) { xm1[i] = 0.f; xm2[i] = 0.f; xm3[i] = 0.f; }
    }

    float4 nxtv = *(const float4*)(srcb);   // 1-deep token prefetch

    if (g < 6) {
        // ---------------- Q / K: conv + RMSNorm + RoPE -> frag-linear
        int j0   = ch & 127;                                 // d-offset within head
        int head = (g < 4) ? (ch >> 7) : ((ch - 2048) >> 7);
        const float* nw = (g < 4) ? qnw : knw;
        float nwv[8];
        {
            float4 na = *(const float4*)(nw + j0);
            float4 nb = *(const float4*)(nw + j0 + 4);
            #pragma unroll
            for (int i = 0; i < 8; ++i) nwv[i] = (i < 4) ? (&na.x)[i] : (&nb.x)[i - 4];
        }
        int ks = (lane >> 2) & 3, qd = lane & 3;             // frag coords from d-offset
        size_t qkbase = ((size_t)((g < 4 ? (b << 4) : (b << 3)) + head) << 18)
                      + ((size_t)(t0 >> 4) << 11) + ((size_t)ks << 9)
                      + ((size_t)qd << 7) + ((size_t)(t0 & 15) << 3);
        bf16* dstb = (g < 4 ? qf : kf) + qkbase;

        int fi0 = j0 & 63;
        bool neg = (j0 < 64);
        const float* ctp = cost + t0 * 64 + fi0;
        const float* stp = sint + t0 * 64 + fi0;

        #pragma unroll
        for (int tt = 0; tt < 8; ++tt) {
            U8 u; u.v = nxtv;
            if (tt < 7) nxtv = *(const float4*)(srcb + (size_t)(tt + 1) * 4096);
            float cur[8], cv[8];
            #pragma unroll
            for (int i = 0; i < 8; ++i) cur[i] = (float)u.h[i];
            #pragma unroll
            for (int i = 0; i < 8; ++i) {
                float a = fmaf(w4[i].x, cur[i], cur[i]);      // x + w0*x[t]
                a = fmaf(w4[i].y, xm1[i], a);
                a = fmaf(w4[i].z, xm2[i], a);
                cv[i] = fmaf(w4[i].w, xm3[i], a);
                xm3[i] = xm2[i]; xm2[i] = xm1[i]; xm1[i] = cur[i];
            }
            // per-head RMS over 16 lanes (128 ch)
            float ss = 0.f;
            #pragma unroll
            for (int i = 0; i < 8; ++i) ss = fmaf(cv[i], cv[i], ss);
            ss += __shfl_xor(ss, 1); ss += __shfl_xor(ss, 2);
            ss += __shfl_xor(ss, 4); ss += __shfl_xor(ss, 8);
            float r1 = rsqrtf(ss * (1.0f / 128.0f) + 1e-6f);
            float xn[8];
            #pragma unroll
            for (int i = 0; i < 8; ++i) xn[i] = cv[i] * r1 * nwv[i];
            // RoPE
            float4 ca = *(const float4*)(ctp + tt * 64);
            float4 cb = *(const float4*)(ctp + tt * 64 + 4);
            float4 sa = *(const float4*)(stp + tt * 64);
            float4 sb = *(const float4*)(stp + tt * 64 + 4);
            __align__(16) bf16 outv[8];
            #pragma unroll
            for (int i = 0; i < 8; ++i) {
                float xp  = __shfl_xor(xn[i], 8);            // partner channel j +/- 64
                float rot = neg ? -xp : xp;
                float cc = (i < 4) ? (&ca.x)[i] : (&cb.x)[i - 4];
                float sn = (i < 4) ? (&sa.x)[i] : (&sb.x)[i - 4];
                outv[i] = (bf16)fmaf(xn[i], cc, rot * sn);
            }
            *(float4*)(dstb + (tt << 3)) = *(const float4*)outv;
        }
    } else {
        // ---------------- V: conv -> LDS tile -> frag-linear (fused repack)
        int lrow0 = (tid >> 6) << 3;              // wave's 8-row slot in the 32-token tile
        #pragma unroll
        for (int tt = 0; tt < 8; ++tt) {
            U8 u; u.v = nxtv;
            if (tt < 7) nxtv = *(const float4*)(srcb + (size_t)(tt + 1) * 4096);
            float cur[8];
            __align__(16) bf16 outv[8];
            #pragma unroll
            for (int i = 0; i < 8; ++i) cur[i] = (float)u.h[i];
            #pragma unroll
            for (int i = 0; i < 8; ++i) {
                float a = fmaf(w4[i].x, cur[i], cur[i]);
                a = fmaf(w4[i].y, xm1[i], a);
                a = fmaf(w4[i].z, xm2[i], a);
                a = fmaf(w4[i].w, xm3[i], a);
                xm3[i] = xm2[i]; xm2[i] = xm1[i]; xm1[i] = cur[i];
                outv[i] = (bf16)a;
            }
            // wave-contiguous 1KB row write: conflict-free
            *(float4*)(&vtile[(lrow0 + tt) * 520 + (lane << 3)]) = *(const float4*)outv;
        }
        __syncthreads();
        // gather: frag element (t,d): quad=(t>>3)&3, j=t&7, lane=quad*16+(d&15), dnt=d>>4
        int T  = (((blockIdx.x * 4) & 255) << 3); // block's first token (32-aligned)
        int kt = T >> 6, ks = (T >> 5) & 1;
        int hb = (g - 6) << 2;                    // head base 0 / 4
        #pragma unroll
        for (int p = 0; p < 8; ++p) {
            int cidx = tid + p * 256;             // 0..2047 = hd*512 + dnt*64 + lane_c
            int hd  = cidx >> 9;
            int dnt = (cidx >> 6) & 7;
            int lc  = cidx & 63;
            int quad = lc >> 4, l16 = lc & 15;
            int scol = hd * 128 + dnt * 16 + l16;
            __align__(16) bf16 outv[8];
            #pragma unroll
            for (int j = 0; j < 8; ++j)
                outv[j] = vtile[(quad * 8 + j) * 520 + scol];
            size_t off = (((size_t)(b * 8 + hb + hd) * 32 + kt) << 13)
                       + ((size_t)ks << 12) + ((size_t)dnt << 9) + ((size_t)lc << 3);
            *(float4*)(vfrag + off) = *(const float4*)outv;
        }
    }
}

// ---------------------------------------------------------------- flash attention (causal, GQA)
// K/V tiles staged once per block into double-buffered LDS via global_load_lds
// (frag-linear layout == linear stage, lane x 16B), shared by all 4 waves:
// 4x less L2 traffic than per-wave global reads. 2-phase async pipeline:
// barrier -> issue next-tile stage -> compute current (stage overlaps compute,
// one vmcnt-drain barrier per tile). Causal mask peeled to the final tile.
// Stage partition: 256 threads x 16B x 4 passes = 16KB tile; per-thread
// element offset tid*8, pass stride 2048 elems (wave-uniform base + lane*16B).
__global__ __launch_bounds__(256) void flash_attn(const bf16* __restrict__ qf,
                                                  const bf16* __restrict__ kf,
                                                  const bf16* __restrict__ vfrag,
                                                  bf16* __restrict__ attn) {
    __shared__ __align__(16) bf16 Kls[2][8192];   // 64 keys x 128 d, frag-linear
    __shared__ __align__(16) bf16 Vls[2][8192];
    __shared__ __align__(16) bf16 Pls[4][16][72];
    int lid  = blockIdx.x;                         // 0..1023
    int pair = lid & 15;                           // (b*8+kvh) -> stable XCD via lid%8
    int b    = pair >> 3, kvh = pair & 7;
    int inner = lid >> 4;                          // 0..63
    int qt   = 31 - (inner >> 1);                  // longest q-tiles first
    int h    = kvh * 2 + (inner & 1);
    int tid = threadIdx.x, wave = tid >> 6, lane = tid & 63;
    int quad = lane >> 4, l16 = lane & 15;
    int qrow0 = (qt << 6) + (wave << 4);

    const bf16* kfp = kf    + (((size_t)b * KVH_ + kvh) << 18);   // 32 kt * 8192
    const bf16* vfp = vfrag + (((size_t)b * KVH_ + kvh) << 18);
    const bf16* qfp = qf    + ((((size_t)(b * H_ + h) * 128 + (qt << 2) + wave)) << 11);

    bf16x8 aq[4];
    #pragma unroll
    for (int ks = 0; ks < 4; ++ks)
        aq[ks] = *(const bf16x8*)(qfp + (ks << 9) + (lane << 3));

    floatx4 o[8] = {};
    float l_i[4] = {0.f, 0.f, 0.f, 0.f};
    const float scl2 = 0.08838834764831845f * 1.4426950408889634f;  // scale*log2(e)

    int ktiles = qt + 1;
    int eo = tid << 3;                 // stage offset: tid*8 elems (lane*16B within wave)

    // prologue: issue stage of tile 0 into buf 0
    #pragma unroll
    for (int i = 0; i < 4; ++i) {
        __builtin_amdgcn_global_load_lds((AS1 const unsigned int*)(kfp + eo + (i << 11)),
                                         (AS3 unsigned int*)(&Kls[0][0] + eo + (i << 11)), 16, 0, 0);
        __builtin_amdgcn_global_load_lds((AS1 const unsigned int*)(vfp + eo + (i << 11)),
                                         (AS3 unsigned int*)(&Vls[0][0] + eo + (i << 11)), 16, 0, 0);
    }

    int cur = 0;
    for (int kt = 0; kt < ktiles; ++kt) {
        __syncthreads();   // drains the stage of buf[cur]; fences prev compute on buf[cur^1]
        if (kt + 1 < ktiles) {
            const bf16* ksrc = kfp + (((size_t)(kt + 1)) << 13) + eo;
            const bf16* vsrc = vfp + (((size_t)(kt + 1)) << 13) + eo;
            bf16* kd = &Kls[cur ^ 1][0] + eo;
            bf16* vd = &Vls[cur ^ 1][0] + eo;
            #pragma unroll
            for (int i = 0; i < 4; ++i) {
                __builtin_amdgcn_global_load_lds((AS1 const unsigned int*)(ksrc + (i << 11)),
                                                 (AS3 unsigned int*)(kd + (i << 11)), 16, 0, 0);
                __builtin_amdgcn_global_load_lds((AS1 const unsigned int*)(vsrc + (i << 11)),
                                                 (AS3 unsigned int*)(vd + (i << 11)), 16, 0, 0);
            }
        }
        const bf16* Kb = &Kls[cur][0];
        const bf16* Vb = &Vls[cur][0];
        // S = Q K^T (K frags from LDS: contiguous 1KB per frag, conflict-free)
        floatx4 sc[4] = {};
        #pragma unroll
        for (int nt = 0; nt < 4; ++nt) {
            #pragma unroll
            for (int ks = 0; ks < 4; ++ks) {
                bf16x8 kb8 = *(const bf16x8*)(Kb + ((nt * 4 + ks) << 9) + (lane << 3));
                sc[nt] = __builtin_amdgcn_mfma_f32_16x16x32_bf16(aq[ks], kb8, sc[nt], 0, 0, 0);
            }
        }
        // p = exp2(s*scl2); mask only on the final (diagonal) tile
        int qr0 = qrow0 + (quad << 2);
        int kb = kt << 6;
        if (kt == ktiles - 1) {
            #pragma unroll
            for (int nt = 0; nt < 4; ++nt) {
                int key = kb + nt * 16 + l16;
                #pragma unroll
                for (int r = 0; r < 4; ++r) {
                    float pv = exp2f(sc[nt][r] * scl2);
                    pv = (key <= qr0 + r) ? pv : 0.f;
                    l_i[r] += pv;
                    Pls[wave][(quad << 2) + r][nt * 16 + l16] = (bf16)pv;
                }
            }
        } else {
            #pragma unroll
            for (int nt = 0; nt < 4; ++nt) {
                #pragma unroll
                for (int r = 0; r < 4; ++r) {
                    float pv = exp2f(sc[nt][r] * scl2);
                    l_i[r] += pv;
                    Pls[wave][(quad << 2) + r][nt * 16 + l16] = (bf16)pv;
                }
            }
        }
        // O += P V (V frags from LDS)
        {
            bf16x8 pa = *(const bf16x8*)(&Pls[wave][l16][(quad << 3)]);
            #pragma unroll
            for (int dnt = 0; dnt < 8; ++dnt) {
                bf16x8 vb = *(const bf16x8*)(Vb + ((size_t)dnt << 9) + (lane << 3));
                o[dnt] = __builtin_amdgcn_mfma_f32_16x16x32_bf16(pa, vb, o[dnt], 0, 0, 0);
            }
            bf16x8 pb = *(const bf16x8*)(&Pls[wave][l16][32 + (quad << 3)]);
            #pragma unroll
            for (int dnt = 0; dnt < 8; ++dnt) {
                bf16x8 vb = *(const bf16x8*)(Vb + ((size_t)(8 + dnt) << 9) + (lane << 3));
                o[dnt] = __builtin_amdgcn_mfma_f32_16x16x32_bf16(pb, vb, o[dnt], 0, 0, 0);
            }
        }
        cur ^= 1;
    }
    // epilogue
    #pragma unroll
    for (int r = 0; r < 4; ++r) {
        float l = l_i[r];
        l += __shfl_xor(l, 1); l += __shfl_xor(l, 2);
        l += __shfl_xor(l, 4); l += __shfl_xor(l, 8);
        l_i[r] = 1.0f / l;
    }
    #pragma unroll
    for (int dnt = 0; dnt < 8; ++dnt) {
        #pragma unroll
        for (int r = 0; r < 4; ++r) {
            size_t row = (size_t)b * S_ + qrow0 + (quad << 2) + r;
            attn[row * D_ + h * DH_ + dnt * 16 + l16] = (bf16)(o[dnt][r] * l_i[r]);
        }
    }
}

// ---------------------------------------------------------------- launch
extern "C" void kernel_launch(void* const* d_in, const int* in_sizes, int n_in,
                              void* d_out, int out_size, void* d_ws, size_t ws_size,
                              hipStream_t stream) {
    const float* hidden = (const float*)d_in[0];
    const float* Wq  = (const float*)d_in[1];
    const float* Wk  = (const float*)d_in[2];
    const float* Wv  = (const float*)d_in[3];
    const float* Wo  = (const float*)d_in[4];
    const float* cqw = (const float*)d_in[5];
    const float* ckw = (const float*)d_in[6];
    const float* cvw = (const float*)d_in[7];
    const float* qnw = (const float*)d_in[8];
    const float* knw = (const float*)d_in[9];

    char* p = (char*)d_ws;
    auto alloc = [&](size_t bytes) { char* r = p; p += (bytes + 255) & ~(size_t)255; return r; };
    bf16*  X    = (bf16*)alloc((size_t)M_ * D_ * 2);
    bf16*  Wcat = (bf16*)alloc((size_t)NQKV_ * D_ * 2);
    bf16*  Wob  = (bf16*)alloc((size_t)D_ * D_ * 2);
    bf16*  QKV  = (bf16*)alloc((size_t)M_ * NQKV_ * 2);
    bf16*  qfb  = (bf16*)alloc((size_t)B_ * H_ * S_ * DH_ * 2);   // frag-linear Q
    bf16*  kfb  = (bf16*)alloc((size_t)B_ * KVH_ * S_ * DH_ * 2); // frag-linear K
    bf16*  vfr  = (bf16*)alloc((size_t)B_ * KVH_ * S_ * DH_ * 2); // frag-linear V
    float* cost = (float*)alloc((size_t)S_ * 64 * 4);
    float* sint = (float*)alloc((size_t)S_ * 64 * 4);
    bf16*  attnb = QKV;   // QKV dead after canon_kernel

    prep_kernel<<<20992, 256, 0, stream>>>(hidden, Wq, Wk, Wv, Wo, X, Wcat, Wob, cost, sint);
    gemm_bt<bf16><<<dim3(NQKV_ / BN, M_ / BM), 256, 0, stream>>>(X, Wcat, QKV, M_, NQKV_, D_);
    canon_kernel<<<1024, 256, 0, stream>>>(QKV, cqw, ckw, cvw, qnw, knw, cost, sint, qfb, kfb, vfr);
    flash_attn<<<1024, 256, 0, stream>>>(qfb, kfb, vfr, attnb);
    gemm_bt<float><<<dim3(D_ / BN, M_ / BM), 256, 0, stream>>>(attnb, Wob, (float*)d_out, M_, D_, D_);
}

// Round 7
// 353.922 us; speedup vs baseline: 1.7667x; 1.0666x over previous
//
#include <hip/hip_runtime.h>
#include <hip/hip_bf16.h>

typedef __bf16 bf16;
typedef __bf16 bf16x8 __attribute__((ext_vector_type(8)));
typedef float  floatx4 __attribute__((ext_vector_type(4)));

#define AS1 __attribute__((address_space(1)))
#define AS3 __attribute__((address_space(3)))

#define B_    2
#define S_    2048
#define D_    2048
#define H_    16
#define KVH_  8
#define DH_   128
#define M_    4096      // B_*S_
#define NQKV_ 4096      // D_ + 2*KVH_*DH_

// ---------------------------------------------------------------- fused prep: all fp32->bf16 casts + RoPE tables
__global__ __launch_bounds__(256) void prep_kernel(const float* __restrict__ hidden,
                                                   const float* __restrict__ Wq,
                                                   const float* __restrict__ Wk,
                                                   const float* __restrict__ Wv,
                                                   const float* __restrict__ Wo,
                                                   bf16* __restrict__ X,
                                                   bf16* __restrict__ Wcat,
                                                   bf16* __restrict__ Wob,
                                                   float* __restrict__ cost,
                                                   float* __restrict__ sint) {
    size_t u = (size_t)blockIdx.x * 256 + threadIdx.x;
    if (u < 5242880) {
        const float* src; bf16* dst; size_t off;
        if (u < 2097152)      { src = hidden; dst = X;              off = u; }
        else if (u < 3145728) { src = Wq;     dst = Wcat;           off = u - 2097152; }
        else if (u < 3670016) { src = Wk;     dst = Wcat + 4194304; off = u - 3145728; }
        else if (u < 4194304) { src = Wv;     dst = Wcat + 6291456; off = u - 3670016; }
        else                  { src = Wo;     dst = Wob;            off = u - 4194304; }
        float4 v = *(const float4*)(src + off * 4);
        union { bf16 h[4]; double d; } uu;
        uu.h[0] = (bf16)v.x; uu.h[1] = (bf16)v.y; uu.h[2] = (bf16)v.z; uu.h[3] = (bf16)v.w;
        *(double*)(dst + off * 4) = uu.d;
    } else {
        int r = (int)(u - 5242880);              // 0..131071
        int t = r >> 6, fi = r & 63;
        float inv = expf(-9.210340371976184f * (float)fi * (1.0f / 64.0f)); // 10000^(-fi/64)
        float ang = (float)t * inv;
        cost[r] = cosf(ang);
        sint[r] = sinf(ang);
    }
}

// ---------------------------------------------------------------- 8-phase 256x256 GEMM (counted vmcnt, 4-deep LDS ring)
// C[M,N] = A[M,K] * B[N,K]^T, bf16 in/out, fp32 acc. BK=32, 8 waves (2Mx4N),
// per-wave 128x64 output. LDS: 4 bufs x (A 16KB + B 16KB) = 128 KiB -> 3-tile
// lookahead, per-tile gate vmcnt(8) (never 0 in main loop). Raw s_barrier
// (no implicit drain); vmcnt check placed BEFORE its barrier so all waves'
// stages are verified landed before any wave reads. Read swizzle: chunk slot
// = quad ^ ((l16^(l16>>2))&3) (2-way residual conflict = free); staged via
// inverse-permuted global source + linear gload_lds dest (both-sides rule).
// Buffer ledger: buf[u&3] last read at tile u phase 1; next writer L(u+4)
// issues during tile u+1 -> race-free by construction.
__global__ __launch_bounds__(512, 2) void gemm_bt8(const bf16* __restrict__ A,
                                                   const bf16* __restrict__ Bw,
                                                   bf16* __restrict__ C,
                                                   int M, int N, int K) {
    __shared__ __align__(16) bf16 Als[4][256 * 32];
    __shared__ __align__(16) bf16 Bls[4][256 * 32];
    int tid  = threadIdx.x;
    int wave = tid >> 6, lane = tid & 63;
    int quad = lane >> 4, l16 = lane & 15;
    int wr = wave >> 2, wc = wave & 3;            // 2 x 4 wave grid

    int nbx = N >> 8;
    int wg  = (blockIdx.x & 7) * ((int)gridDim.x >> 3) + (blockIdx.x >> 3); // bijective (grid%8==0)
    int by  = wg / nbx, bx = wg % nbx;
    long bm0 = (long)by << 8, bn0 = (long)bx << 8;

    // read-side swizzle slot (lane-constant: row&3 == l16&3, (row>>2)&3 == (l16>>2)&3 for 16-aligned bases)
    int slot8 = ((quad ^ ((l16 ^ (l16 >> 2)) & 3)) << 3);

    // stage addressing: chunk c = tid (+512); row=c>>2, lds slot=c&3, src chunk=(c&3)^xr(row)
    int srow   = tid >> 2;                        // 0..127 (load1: +128, same xr)
    int schunk = (tid & 3) ^ ((srow ^ (srow >> 2)) & 3);
    const bf16* Asrc = A  + (bm0 + srow) * K + schunk * 8;
    const bf16* Bsrc = Bw + (bn0 + srow) * K + schunk * 8;
    size_t ldoff = (size_t)128 * K;               // second-load source row offset

    floatx4 acc[8][4] = {};
    int NT = K >> 5;

#define STAGE_A8(t) { int d_ = (t) & 3; long k0_ = (long)(t) << 5;                                   \
    __builtin_amdgcn_global_load_lds((AS1 const unsigned int*)(Asrc + k0_),                          \
                                     (AS3 unsigned int*)(&Als[d_][0] + tid * 8), 16, 0, 0);          \
    __builtin_amdgcn_global_load_lds((AS1 const unsigned int*)(Asrc + ldoff + k0_),                  \
                                     (AS3 unsigned int*)(&Als[d_][0] + tid * 8 + 4096), 16, 0, 0); }
#define STAGE_B8(t) { int d_ = (t) & 3; long k0_ = (long)(t) << 5;                                   \
    __builtin_amdgcn_global_load_lds((AS1 const unsigned int*)(Bsrc + k0_),                          \
                                     (AS3 unsigned int*)(&Bls[d_][0] + tid * 8), 16, 0, 0);          \
    __builtin_amdgcn_global_load_lds((AS1 const unsigned int*)(Bsrc + ldoff + k0_),                  \
                                     (AS3 unsigned int*)(&Bls[d_][0] + tid * 8 + 4096), 16, 0, 0); }

    // prologue: stage tiles 0,1,2 in order; gate tile 0 (8 newest may stay in flight)
    STAGE_A8(0); STAGE_B8(0);
    STAGE_A8(1); STAGE_B8(1);
    STAGE_A8(2); STAGE_B8(2);
    asm volatile("s_waitcnt vmcnt(8)" ::: "memory");
    __builtin_amdgcn_s_barrier();

    for (int u = 0; u < NT; ++u) {
        const bf16* Ab = &Als[u & 3][0];
        const bf16* Bb = &Bls[u & 3][0];
        bf16x8 af[4], bfr[4];
        // ---- phase 0 (rows wr*128 + 0..63)
        #pragma unroll
        for (int mt = 0; mt < 4; ++mt) {
            int row = wr * 128 + mt * 16 + l16;
            af[mt] = *(const bf16x8*)(Ab + row * 32 + slot8);
        }
        #pragma unroll
        for (int nt = 0; nt < 4; ++nt) {
            int col = wc * 64 + nt * 16 + l16;
            bfr[nt] = *(const bf16x8*)(Bb + col * 32 + slot8);
        }
        if (u + 3 < NT) { STAGE_A8(u + 3); }
        __builtin_amdgcn_s_barrier();
        asm volatile("s_waitcnt lgkmcnt(0)" ::: "memory");
        __builtin_amdgcn_sched_barrier(0);
        __builtin_amdgcn_s_setprio(1);
        #pragma unroll
        for (int mt = 0; mt < 4; ++mt)
            #pragma unroll
            for (int nt = 0; nt < 4; ++nt)
                acc[mt][nt] = __builtin_amdgcn_mfma_f32_16x16x32_bf16(af[mt], bfr[nt], acc[mt][nt], 0, 0, 0);
        __builtin_amdgcn_s_setprio(0);
        __builtin_amdgcn_s_barrier();
        // ---- phase 1 (rows wr*128 + 64..127; B frags reused from regs)
        #pragma unroll
        for (int mt = 0; mt < 4; ++mt) {
            int row = wr * 128 + 64 + mt * 16 + l16;
            af[mt] = *(const bf16x8*)(Ab + row * 32 + slot8);
        }
        if (u + 3 < NT) { STAGE_B8(u + 3); }
        if (u < NT - 3)       { asm volatile("s_waitcnt vmcnt(8)" ::: "memory"); }
        else if (u == NT - 3) { asm volatile("s_waitcnt vmcnt(4)" ::: "memory"); }
        else                  { asm volatile("s_waitcnt vmcnt(0)" ::: "memory"); }
        __builtin_amdgcn_s_barrier();
        asm volatile("s_waitcnt lgkmcnt(0)" ::: "memory");
        __builtin_amdgcn_sched_barrier(0);
        __builtin_amdgcn_s_setprio(1);
        #pragma unroll
        for (int mt = 0; mt < 4; ++mt)
            #pragma unroll
            for (int nt = 0; nt < 4; ++nt)
                acc[4 + mt][nt] = __builtin_amdgcn_mfma_f32_16x16x32_bf16(af[mt], bfr[nt], acc[4 + mt][nt], 0, 0, 0);
        __builtin_amdgcn_s_setprio(0);
        __builtin_amdgcn_s_barrier();
    }
#undef STAGE_A8
#undef STAGE_B8
    // epilogue
    #pragma unroll
    for (int am = 0; am < 8; ++am) {
        #pragma unroll
        for (int nt = 0; nt < 4; ++nt) {
            long row = bm0 + wr * 128 + (am >> 2) * 64 + (am & 3) * 16 + quad * 4;
            long col = bn0 + wc * 64 + nt * 16 + l16;
            #pragma unroll
            for (int r = 0; r < 4; ++r)
                C[(row + r) * N + col] = (bf16)acc[am][nt][r];
        }
    }
}

// ---------------------------------------------------------------- GEMM: C[M,N] = A[M,K] * B[N,K]^T   (bf16 in, fp32 acc, CT out)
#define BM 128
#define BN 128
#define BK 64
template <typename CT>
__global__ __launch_bounds__(256) void gemm_bt(const bf16* __restrict__ A,
                                               const bf16* __restrict__ Bw,
                                               CT* __restrict__ C,
                                               int M, int N, int K) {
    __shared__ __align__(16) bf16 Als[BM * BK];
    __shared__ __align__(16) bf16 Bls[BN * BK];
    int tid  = threadIdx.x;
    int wave = tid >> 6, lane = tid & 63;
    int quad = lane >> 4, l16 = lane & 15;
    int wm = (wave >> 1) << 6;   // 0 / 64
    int wn = (wave & 1) << 6;

    long bm0 = (long)blockIdx.y * BM;
    long bn0 = (long)blockIdx.x * BN;
    const bf16* Ab = A  + bm0 * K;
    const bf16* Bb = Bw + bn0 * K;

    int srow = wave * 32 + (lane >> 3);
    int scol = ((lane & 7) ^ (lane >> 3)) << 3;
    int sdst = (wave * 32 + (lane >> 3)) * BK + ((lane & 7) << 3);

    floatx4 acc[4][4] = {};

    for (int k0 = 0; k0 < K; k0 += BK) {
        #pragma unroll
        for (int i = 0; i < 4; ++i) {
            const bf16* ga = Ab + (long)(srow + i * 8) * K + k0 + scol;
            const bf16* gb = Bb + (long)(srow + i * 8) * K + k0 + scol;
            __builtin_amdgcn_global_load_lds((AS1 const unsigned int*)ga,
                                             (AS3 unsigned int*)(Als + sdst + i * 512), 16, 0, 0);
            __builtin_amdgcn_global_load_lds((AS1 const unsigned int*)gb,
                                             (AS3 unsigned int*)(Bls + sdst + i * 512), 16, 0, 0);
        }
        __syncthreads();
        #pragma unroll
        for (int ks = 0; ks < 2; ++ks) {
            bf16x8 af[4], bfr[4];
            #pragma unroll
            for (int t = 0; t < 4; ++t) {
                int row = wm + t * 16 + l16;
                int g = (ks * 4 + quad) ^ (row & 7);
                af[t] = *(const bf16x8*)(Als + row * BK + (g << 3));
            }
            #pragma unroll
            for (int t = 0; t < 4; ++t) {
                int row = wn + t * 16 + l16;
                int g = (ks * 4 + quad) ^ (row & 7);
                bfr[t] = *(const bf16x8*)(Bls + row * BK + (g << 3));
            }
            #pragma unroll
            for (int mt = 0; mt < 4; ++mt)
                #pragma unroll
                for (int nt = 0; nt < 4; ++nt)
                    acc[mt][nt] = __builtin_amdgcn_mfma_f32_16x16x32_bf16(af[mt], bfr[nt], acc[mt][nt], 0, 0, 0);
        }
        __syncthreads();
    }
    #pragma unroll
    for (int mt = 0; mt < 4; ++mt) {
        #pragma unroll
        for (int nt = 0; nt < 4; ++nt) {
            long row = bm0 + wm + mt * 16 + quad * 4;
            long col = bn0 + wn + nt * 16 + l16;
            #pragma unroll
            for (int r = 0; r < 4; ++r)
                C[(row + r) * N + col] = (CT)acc[mt][nt][r];
        }
    }
}

// ---------------------------------------------------------------- canon_b + RMSNorm + RoPE (token-streaming) + fused V repack
__global__ __launch_bounds__(256, 4) void canon_kernel(const bf16* __restrict__ QKV,
                                                       const float* __restrict__ wq,
                                                       const float* __restrict__ wk,
                                                       const float* __restrict__ wv,
                                                       const float* __restrict__ qnw,
                                                       const float* __restrict__ knw,
                                                       const float* __restrict__ cost,
                                                       const float* __restrict__ sint,
                                                       bf16* __restrict__ qf,
                                                       bf16* __restrict__ kf,
                                                       bf16* __restrict__ vfrag) {
    __shared__ __align__(16) bf16 vtile[32 * 520];   // V blocks only; 520 = 16B-aligned pad
    int tid  = threadIdx.x;
    int wid  = blockIdx.x * 4 + (tid >> 6);
    int lane = tid & 63;
    int b  = wid >> 11;              // 2048 waves per batch
    int g  = (wid >> 8) & 7;         // 512-channel group (0-3 q, 4-5 k, 6-7 v); block-uniform
    int c  = wid & 255;              // 8-token chunk
    int t0 = c << 3;
    int ch = (g << 9) + (lane << 3); // column in QKV row

    const float* wrow; int cw;
    if (g < 4)      { wrow = wq; cw = ch; }
    else if (g < 6) { wrow = wk; cw = ch - 2048; }
    else            { wrow = wv; cw = ch - 3072; }

    float4 w4[8];                    // w4[i] = {w0,w1,w2,w3} of channel ch+i
    #pragma unroll
    for (int j = 0; j < 8; ++j) w4[j] = *(const float4*)(wrow + (cw + j) * 4);

    union U8 { float4 v; bf16 h[8]; };
    const bf16* srcb = QKV + (size_t)((b << 11) + t0) * 4096 + ch;

    // conv window x[t-1], x[t-2], x[t-3]
    float xm1[8], xm2[8], xm3[8];
    if (t0 > 0) {
        U8 u1, u2, u3;
        u1.v = *(const float4*)(srcb - 4096);
        u2.v = *(const float4*)(srcb - 2 * 4096);
        u3.v = *(const float4*)(srcb - 3 * 4096);
        #pragma unroll
        for (int i = 0; i < 8; ++i) {
            xm1[i] = (float)u1.h[i]; xm2[i] = (float)u2.h[i]; xm3[i] = (float)u3.h[i];
        }
    } else {
        #pragma unroll
        for (int i = 0; i < 8; ++i) { xm1[i] = 0.f; xm2[i] = 0.f; xm3[i] = 0.f; }
    }

    float4 nxtv = *(const float4*)(srcb);   // 1-deep token prefetch

    if (g < 6) {
        // ---------------- Q / K: conv + RMSNorm + RoPE -> frag-linear
        int j0   = ch & 127;                                 // d-offset within head
        int head = (g < 4) ? (ch >> 7) : ((ch - 2048) >> 7);
        const float* nw = (g < 4) ? qnw : knw;
        float nwv[8];
        {
            float4 na = *(const float4*)(nw + j0);
            float4 nb = *(const float4*)(nw + j0 + 4);
            #pragma unroll
            for (int i = 0; i < 8; ++i) nwv[i] = (i < 4) ? (&na.x)[i] : (&nb.x)[i - 4];
        }
        int ks = (lane >> 2) & 3, qd = lane & 3;             // frag coords from d-offset
        size_t qkbase = ((size_t)((g < 4 ? (b << 4) : (b << 3)) + head) << 18)
                      + ((size_t)(t0 >> 4) << 11) + ((size_t)ks << 9)
                      + ((size_t)qd << 7) + ((size_t)(t0 & 15) << 3);
        bf16* dstb = (g < 4 ? qf : kf) + qkbase;

        int fi0 = j0 & 63;
        bool neg = (j0 < 64);
        const float* ctp = cost + t0 * 64 + fi0;
        const float* stp = sint + t0 * 64 + fi0;

        #pragma unroll
        for (int tt = 0; tt < 8; ++tt) {
            U8 u; u.v = nxtv;
            if (tt < 7) nxtv = *(const float4*)(srcb + (size_t)(tt + 1) * 4096);
            float cur[8], cv[8];
            #pragma unroll
            for (int i = 0; i < 8; ++i) cur[i] = (float)u.h[i];
            #pragma unroll
            for (int i = 0; i < 8; ++i) {
                float a = fmaf(w4[i].x, cur[i], cur[i]);      // x + w0*x[t]
                a = fmaf(w4[i].y, xm1[i], a);
                a = fmaf(w4[i].z, xm2[i], a);
                cv[i] = fmaf(w4[i].w, xm3[i], a);
                xm3[i] = xm2[i]; xm2[i] = xm1[i]; xm1[i] = cur[i];
            }
            // per-head RMS over 16 lanes (128 ch)
            float ss = 0.f;
            #pragma unroll
            for (int i = 0; i < 8; ++i) ss = fmaf(cv[i], cv[i], ss);
            ss += __shfl_xor(ss, 1); ss += __shfl_xor(ss, 2);
            ss += __shfl_xor(ss, 4); ss += __shfl_xor(ss, 8);
            float r1 = rsqrtf(ss * (1.0f / 128.0f) + 1e-6f);
            float xn[8];
            #pragma unroll
            for (int i = 0; i < 8; ++i) xn[i] = cv[i] * r1 * nwv[i];
            // RoPE
            float4 ca = *(const float4*)(ctp + tt * 64);
            float4 cb = *(const float4*)(ctp + tt * 64 + 4);
            float4 sa = *(const float4*)(stp + tt * 64);
            float4 sb = *(const float4*)(stp + tt * 64 + 4);
            __align__(16) bf16 outv[8];
            #pragma unroll
            for (int i = 0; i < 8; ++i) {
                float xp  = __shfl_xor(xn[i], 8);            // partner channel j +/- 64
                float rot = neg ? -xp : xp;
                float cc = (i < 4) ? (&ca.x)[i] : (&cb.x)[i - 4];
                float sn = (i < 4) ? (&sa.x)[i] : (&sb.x)[i - 4];
                outv[i] = (bf16)fmaf(xn[i], cc, rot * sn);
            }
            *(float4*)(dstb + (tt << 3)) = *(const float4*)outv;
        }
    } else {
        // ---------------- V: conv -> LDS tile -> frag-linear (fused repack)
        int lrow0 = (tid >> 6) << 3;              // wave's 8-row slot in the 32-token tile
        #pragma unroll
        for (int tt = 0; tt < 8; ++tt) {
            U8 u; u.v = nxtv;
            if (tt < 7) nxtv = *(const float4*)(srcb + (size_t)(tt + 1) * 4096);
            float cur[8];
            __align__(16) bf16 outv[8];
            #pragma unroll
            for (int i = 0; i < 8; ++i) cur[i] = (float)u.h[i];
            #pragma unroll
            for (int i = 0; i < 8; ++i) {
                float a = fmaf(w4[i].x, cur[i], cur[i]);
                a = fmaf(w4[i].y, xm1[i], a);
                a = fmaf(w4[i].z, xm2[i], a);
                a = fmaf(w4[i].w, xm3[i], a);
                xm3[i] = xm2[i]; xm2[i] = xm1[i]; xm1[i] = cur[i];
                outv[i] = (bf16)a;
            }
            // wave-contiguous 1KB row write: conflict-free
            *(float4*)(&vtile[(lrow0 + tt) * 520 + (lane << 3)]) = *(const float4*)outv;
        }
        __syncthreads();
        // gather: frag element (t,d): quad=(t>>3)&3, j=t&7, lane=quad*16+(d&15), dnt=d>>4
        int T  = (((blockIdx.x * 4) & 255) << 3); // block's first token (32-aligned)
        int kt = T >> 6, ks = (T >> 5) & 1;
        int hb = (g - 6) << 2;                    // head base 0 / 4
        #pragma unroll
        for (int p = 0; p < 8; ++p) {
            int cidx = tid + p * 256;             // 0..2047 = hd*512 + dnt*64 + lane_c
            int hd  = cidx >> 9;
            int dnt = (cidx >> 6) & 7;
            int lc  = cidx & 63;
            int quad = lc >> 4, l16 = lc & 15;
            int scol = hd * 128 + dnt * 16 + l16;
            __align__(16) bf16 outv[8];
            #pragma unroll
            for (int j = 0; j < 8; ++j)
                outv[j] = vtile[(quad * 8 + j) * 520 + scol];
            size_t off = (((size_t)(b * 8 + hb + hd) * 32 + kt) << 13)
                       + ((size_t)ks << 12) + ((size_t)dnt << 9) + ((size_t)lc << 3);
            *(float4*)(vfrag + off) = *(const float4*)outv;
        }
    }
}

// ---------------------------------------------------------------- flash attention (causal, GQA)
__global__ __launch_bounds__(256) void flash_attn(const bf16* __restrict__ qf,
                                                  const bf16* __restrict__ kf,
                                                  const bf16* __restrict__ vfrag,
                                                  bf16* __restrict__ attn) {
    __shared__ __align__(16) bf16 Kls[2][8192];   // 64 keys x 128 d, frag-linear
    __shared__ __align__(16) bf16 Vls[2][8192];
    __shared__ __align__(16) bf16 Pls[4][16][72];
    int lid  = blockIdx.x;                         // 0..1023
    int pair = lid & 15;                           // (b*8+kvh) -> stable XCD via lid%8
    int b    = pair >> 3, kvh = pair & 7;
    int inner = lid >> 4;                          // 0..63
    int qt   = 31 - (inner >> 1);                  // longest q-tiles first
    int h    = kvh * 2 + (inner & 1);
    int tid = threadIdx.x, wave = tid >> 6, lane = tid & 63;
    int quad = lane >> 4, l16 = lane & 15;
    int qrow0 = (qt << 6) + (wave << 4);

    const bf16* kfp = kf    + (((size_t)b * KVH_ + kvh) << 18);   // 32 kt * 8192
    const bf16* vfp = vfrag + (((size_t)b * KVH_ + kvh) << 18);
    const bf16* qfp = qf    + ((((size_t)(b * H_ + h) * 128 + (qt << 2) + wave)) << 11);

    bf16x8 aq[4];
    #pragma unroll
    for (int ks = 0; ks < 4; ++ks)
        aq[ks] = *(const bf16x8*)(qfp + (ks << 9) + (lane << 3));

    floatx4 o[8] = {};
    float l_i[4] = {0.f, 0.f, 0.f, 0.f};
    const float scl2 = 0.08838834764831845f * 1.4426950408889634f;  // scale*log2(e)

    int ktiles = qt + 1;
    int eo = tid << 3;                 // stage offset: tid*8 elems (lane*16B within wave)

    // prologue: issue stage of tile 0 into buf 0
    #pragma unroll
    for (int i = 0; i < 4; ++i) {
        __builtin_amdgcn_global_load_lds((AS1 const unsigned int*)(kfp + eo + (i << 11)),
                                         (AS3 unsigned int*)(&Kls[0][0] + eo + (i << 11)), 16, 0, 0);
        __builtin_amdgcn_global_load_lds((AS1 const unsigned int*)(vfp + eo + (i << 11)),
                                         (AS3 unsigned int*)(&Vls[0][0] + eo + (i << 11)), 16, 0, 0);
    }

    int cur = 0;
    for (int kt = 0; kt < ktiles; ++kt) {
        __syncthreads();   // drains the stage of buf[cur]; fences prev compute on buf[cur^1]
        if (kt + 1 < ktiles) {
            const bf16* ksrc = kfp + (((size_t)(kt + 1)) << 13) + eo;
            const bf16* vsrc = vfp + (((size_t)(kt + 1)) << 13) + eo;
            bf16* kd = &Kls[cur ^ 1][0] + eo;
            bf16* vd = &Vls[cur ^ 1][0] + eo;
            #pragma unroll
            for (int i = 0; i < 4; ++i) {
                __builtin_amdgcn_global_load_lds((AS1 const unsigned int*)(ksrc + (i << 11)),
                                                 (AS3 unsigned int*)(kd + (i << 11)), 16, 0, 0);
                __builtin_amdgcn_global_load_lds((AS1 const unsigned int*)(vsrc + (i << 11)),
                                                 (AS3 unsigned int*)(vd + (i << 11)), 16, 0, 0);
            }
        }
        const bf16* Kb = &Kls[cur][0];
        const bf16* Vb = &Vls[cur][0];
        // S = Q K^T (K frags from LDS: contiguous 1KB per frag, conflict-free)
        floatx4 sc[4] = {};
        #pragma unroll
        for (int nt = 0; nt < 4; ++nt) {
            #pragma unroll
            for (int ks = 0; ks < 4; ++ks) {
                bf16x8 kb8 = *(const bf16x8*)(Kb + ((nt * 4 + ks) << 9) + (lane << 3));
                sc[nt] = __builtin_amdgcn_mfma_f32_16x16x32_bf16(aq[ks], kb8, sc[nt], 0, 0, 0);
            }
        }
        // p = exp2(s*scl2); mask only on the final (diagonal) tile
        int qr0 = qrow0 + (quad << 2);
        int kb = kt << 6;
        if (kt == ktiles - 1) {
            #pragma unroll
            for (int nt = 0; nt < 4; ++nt) {
                int key = kb + nt * 16 + l16;
                #pragma unroll
                for (int r = 0; r < 4; ++r) {
                    float pv = exp2f(sc[nt][r] * scl2);
                    pv = (key <= qr0 + r) ? pv : 0.f;
                    l_i[r] += pv;
                    Pls[wave][(quad << 2) + r][nt * 16 + l16] = (bf16)pv;
                }
            }
        } else {
            #pragma unroll
            for (int nt = 0; nt < 4; ++nt) {
                #pragma unroll
                for (int r = 0; r < 4; ++r) {
                    float pv = exp2f(sc[nt][r] * scl2);
                    l_i[r] += pv;
                    Pls[wave][(quad << 2) + r][nt * 16 + l16] = (bf16)pv;
                }
            }
        }
        // O += P V (V frags from LDS)
        {
            bf16x8 pa = *(const bf16x8*)(&Pls[wave][l16][(quad << 3)]);
            #pragma unroll
            for (int dnt = 0; dnt < 8; ++dnt) {
                bf16x8 vb = *(const bf16x8*)(Vb + ((size_t)dnt << 9) + (lane << 3));
                o[dnt] = __builtin_amdgcn_mfma_f32_16x16x32_bf16(pa, vb, o[dnt], 0, 0, 0);
            }
            bf16x8 pb = *(const bf16x8*)(&Pls[wave][l16][32 + (quad << 3)]);
            #pragma unroll
            for (int dnt = 0; dnt < 8; ++dnt) {
                bf16x8 vb = *(const bf16x8*)(Vb + ((size_t)(8 + dnt) << 9) + (lane << 3));
                o[dnt] = __builtin_amdgcn_mfma_f32_16x16x32_bf16(pb, vb, o[dnt], 0, 0, 0);
            }
        }
        cur ^= 1;
    }
    // epilogue
    #pragma unroll
    for (int r = 0; r < 4; ++r) {
        float l = l_i[r];
        l += __shfl_xor(l, 1); l += __shfl_xor(l, 2);
        l += __shfl_xor(l, 4); l += __shfl_xor(l, 8);
        l_i[r] = 1.0f / l;
    }
    #pragma unroll
    for (int dnt = 0; dnt < 8; ++dnt) {
        #pragma unroll
        for (int r = 0; r < 4; ++r) {
            size_t row = (size_t)b * S_ + qrow0 + (quad << 2) + r;
            attn[row * D_ + h * DH_ + dnt * 16 + l16] = (bf16)(o[dnt][r] * l_i[r]);
        }
    }
}

// ---------------------------------------------------------------- launch
extern "C" void kernel_launch(void* const* d_in, const int* in_sizes, int n_in,
                              void* d_out, int out_size, void* d_ws, size_t ws_size,
                              hipStream_t stream) {
    const float* hidden = (const float*)d_in[0];
    const float* Wq  = (const float*)d_in[1];
    const float* Wk  = (const float*)d_in[2];
    const float* Wv  = (const float*)d_in[3];
    const float* Wo  = (const float*)d_in[4];
    const float* cqw = (const float*)d_in[5];
    const float* ckw = (const float*)d_in[6];
    const float* cvw = (const float*)d_in[7];
    const float* qnw = (const float*)d_in[8];
    const float* knw = (const float*)d_in[9];

    char* p = (char*)d_ws;
    auto alloc = [&](size_t bytes) { char* r = p; p += (bytes + 255) & ~(size_t)255; return r; };
    bf16*  X    = (bf16*)alloc((size_t)M_ * D_ * 2);
    bf16*  Wcat = (bf16*)alloc((size_t)NQKV_ * D_ * 2);
    bf16*  Wob  = (bf16*)alloc((size_t)D_ * D_ * 2);
    bf16*  QKV  = (bf16*)alloc((size_t)M_ * NQKV_ * 2);
    bf16*  qfb  = (bf16*)alloc((size_t)B_ * H_ * S_ * DH_ * 2);   // frag-linear Q
    bf16*  kfb  = (bf16*)alloc((size_t)B_ * KVH_ * S_ * DH_ * 2); // frag-linear K
    bf16*  vfr  = (bf16*)alloc((size_t)B_ * KVH_ * S_ * DH_ * 2); // frag-linear V
    float* cost = (float*)alloc((size_t)S_ * 64 * 4);
    float* sint = (float*)alloc((size_t)S_ * 64 * 4);
    bf16*  attnb = QKV;   // QKV dead after canon_kernel

    prep_kernel<<<20992, 256, 0, stream>>>(hidden, Wq, Wk, Wv, Wo, X, Wcat, Wob, cost, sint);
    gemm_bt8<<<(M_ / 256) * (NQKV_ / 256), 512, 0, stream>>>(X, Wcat, QKV, M_, NQKV_, D_);
    canon_kernel<<<1024, 256, 0, stream>>>(QKV, cqw, ckw, cvw, qnw, knw, cost, sint, qfb, kfb, vfr);
    flash_attn<<<1024, 256, 0, stream>>>(qfb, kfb, vfr, attnb);
    gemm_bt<float><<<dim3(D_ / BN, M_ / BM), 256, 0, stream>>>(attnb, Wob, (float*)d_out, M_, D_, D_);
}

// Round 8
// 344.638 us; speedup vs baseline: 1.8143x; 1.0269x over previous
//
#include <hip/hip_runtime.h>
#include <hip/hip_bf16.h>

typedef __bf16 bf16;
typedef __bf16 bf16x8 __attribute__((ext_vector_type(8)));
typedef float  floatx4 __attribute__((ext_vector_type(4)));

#define AS1 __attribute__((address_space(1)))
#define AS3 __attribute__((address_space(3)))

#define B_    2
#define S_    2048
#define D_    2048
#define H_    16
#define KVH_  8
#define DH_   128
#define M_    4096      // B_*S_
#define NQKV_ 4096      // D_ + 2*KVH_*DH_

// ---------------------------------------------------------------- fused prep: all fp32->bf16 casts + RoPE tables
__global__ __launch_bounds__(256) void prep_kernel(const float* __restrict__ hidden,
                                                   const float* __restrict__ Wq,
                                                   const float* __restrict__ Wk,
                                                   const float* __restrict__ Wv,
                                                   const float* __restrict__ Wo,
                                                   bf16* __restrict__ X,
                                                   bf16* __restrict__ Wcat,
                                                   bf16* __restrict__ Wob,
                                                   float* __restrict__ cost,
                                                   float* __restrict__ sint) {
    size_t u = (size_t)blockIdx.x * 256 + threadIdx.x;
    if (u < 5242880) {
        const float* src; bf16* dst; size_t off;
        if (u < 2097152)      { src = hidden; dst = X;              off = u; }
        else if (u < 3145728) { src = Wq;     dst = Wcat;           off = u - 2097152; }
        else if (u < 3670016) { src = Wk;     dst = Wcat + 4194304; off = u - 3145728; }
        else if (u < 4194304) { src = Wv;     dst = Wcat + 6291456; off = u - 3670016; }
        else                  { src = Wo;     dst = Wob;            off = u - 4194304; }
        float4 v = *(const float4*)(src + off * 4);
        union { bf16 h[4]; double d; } uu;
        uu.h[0] = (bf16)v.x; uu.h[1] = (bf16)v.y; uu.h[2] = (bf16)v.z; uu.h[3] = (bf16)v.w;
        *(double*)(dst + off * 4) = uu.d;
    } else {
        int r = (int)(u - 5242880);              // 0..131071
        int t = r >> 6, fi = r & 63;
        float inv = expf(-9.210340371976184f * (float)fi * (1.0f / 64.0f)); // 10000^(-fi/64)
        float ang = (float)t * inv;
        cost[r] = cosf(ang);
        sint[r] = sinf(ang);
    }
}

// ---------------------------------------------------------------- merged-phase 256x256 GEMM (counted vmcnt, 4-deep LDS ring)
// C[M,N] = A[M,K] * B[N,K]^T, bf16 in/out, fp32 acc. BK=32, 8 waves (2Mx4N),
// per-wave 128x64 output. LDS: 4 bufs x (A 16KB + B 16KB) = 128 KiB -> 3-tile
// lookahead, per-tile gate vmcnt(8) (never 0 in main loop). ONE barrier pair
// and ONE lgkmcnt drain per K-tile: 12 ds_reads + 4 stage-issues + vmcnt gate
// -> barrier -> lgkmcnt(0) -> 32-MFMA burst -> barrier. (R7 post-mortem:
// 4 barriers/tile at 8 MFMA/barrier left MfmaUtil at 33% -- sync granularity,
// not memory, was the limiter.) Raw s_barrier (no implicit drain); vmcnt gate
// BEFORE its barrier so all waves' stages are verified before any wave reads.
// Read swizzle: chunk slot = quad ^ ((l16^(l16>>2))&3), lane-constant, staged
// via inverse-permuted global source + linear gload_lds dest (both-sides).
// WAR ledger: buf[(u+3)&3] was last read at tile u-1, confirmed by that
// tile's lgkmcnt(0) + closing barrier before tile u issues the overwrite.
__global__ __launch_bounds__(512, 2) void gemm_bt8(const bf16* __restrict__ A,
                                                   const bf16* __restrict__ Bw,
                                                   bf16* __restrict__ C,
                                                   int M, int N, int K) {
    __shared__ __align__(16) bf16 Als[4][256 * 32];
    __shared__ __align__(16) bf16 Bls[4][256 * 32];
    int tid  = threadIdx.x;
    int wave = tid >> 6, lane = tid & 63;
    int quad = lane >> 4, l16 = lane & 15;
    int wr = wave >> 2, wc = wave & 3;            // 2 x 4 wave grid

    int nbx = N >> 8;
    int wg  = (blockIdx.x & 7) * ((int)gridDim.x >> 3) + (blockIdx.x >> 3); // bijective (grid%8==0)
    int by  = wg / nbx, bx = wg % nbx;
    long bm0 = (long)by << 8, bn0 = (long)bx << 8;

    // read-side swizzle slot (lane-constant: row&3 == l16&3, (row>>2)&3 == (l16>>2)&3 for 16-aligned bases)
    int slot8 = ((quad ^ ((l16 ^ (l16 >> 2)) & 3)) << 3);

    // stage addressing: chunk c = tid (+512); row=c>>2, lds slot=c&3, src chunk=(c&3)^xr(row)
    int srow   = tid >> 2;                        // 0..127 (load1: +128, same xr)
    int schunk = (tid & 3) ^ ((srow ^ (srow >> 2)) & 3);
    const bf16* Asrc = A  + (bm0 + srow) * K + schunk * 8;
    const bf16* Bsrc = Bw + (bn0 + srow) * K + schunk * 8;
    size_t ldoff = (size_t)128 * K;               // second-load source row offset

    floatx4 acc[8][4] = {};
    int NT = K >> 5;

#define STAGE_A8(t) { int d_ = (t) & 3; long k0_ = (long)(t) << 5;                                   \
    __builtin_amdgcn_global_load_lds((AS1 const unsigned int*)(Asrc + k0_),                          \
                                     (AS3 unsigned int*)(&Als[d_][0] + tid * 8), 16, 0, 0);          \
    __builtin_amdgcn_global_load_lds((AS1 const unsigned int*)(Asrc + ldoff + k0_),                  \
                                     (AS3 unsigned int*)(&Als[d_][0] + tid * 8 + 4096), 16, 0, 0); }
#define STAGE_B8(t) { int d_ = (t) & 3; long k0_ = (long)(t) << 5;                                   \
    __builtin_amdgcn_global_load_lds((AS1 const unsigned int*)(Bsrc + k0_),                          \
                                     (AS3 unsigned int*)(&Bls[d_][0] + tid * 8), 16, 0, 0);          \
    __builtin_amdgcn_global_load_lds((AS1 const unsigned int*)(Bsrc + ldoff + k0_),                  \
                                     (AS3 unsigned int*)(&Bls[d_][0] + tid * 8 + 4096), 16, 0, 0); }

    // prologue: stage tiles 0,1,2 in order; gate tile 0 (8 newest may stay in flight)
    STAGE_A8(0); STAGE_B8(0);
    STAGE_A8(1); STAGE_B8(1);
    STAGE_A8(2); STAGE_B8(2);
    asm volatile("s_waitcnt vmcnt(8)" ::: "memory");
    __builtin_amdgcn_s_barrier();

    for (int u = 0; u < NT; ++u) {
        const bf16* Ab = &Als[u & 3][0];
        const bf16* Bb = &Bls[u & 3][0];
        bf16x8 af[8], bfr[4];
        #pragma unroll
        for (int mt = 0; mt < 8; ++mt) {
            int row = wr * 128 + mt * 16 + l16;
            af[mt] = *(const bf16x8*)(Ab + row * 32 + slot8);
        }
        #pragma unroll
        for (int nt = 0; nt < 4; ++nt) {
            int col = wc * 64 + nt * 16 + l16;
            bfr[nt] = *(const bf16x8*)(Bb + col * 32 + slot8);
        }
        if (u + 3 < NT) { STAGE_A8(u + 3); STAGE_B8(u + 3); }
        if (u < NT - 3)       { asm volatile("s_waitcnt vmcnt(8)" ::: "memory"); }
        else if (u == NT - 3) { asm volatile("s_waitcnt vmcnt(4)" ::: "memory"); }
        else                  { asm volatile("s_waitcnt vmcnt(0)" ::: "memory"); }
        __builtin_amdgcn_s_barrier();
        asm volatile("s_waitcnt lgkmcnt(0)" ::: "memory");
        __builtin_amdgcn_sched_barrier(0);
        __builtin_amdgcn_s_setprio(1);
        #pragma unroll
        for (int mt = 0; mt < 8; ++mt)
            #pragma unroll
            for (int nt = 0; nt < 4; ++nt)
                acc[mt][nt] = __builtin_amdgcn_mfma_f32_16x16x32_bf16(af[mt], bfr[nt], acc[mt][nt], 0, 0, 0);
        __builtin_amdgcn_s_setprio(0);
        __builtin_amdgcn_s_barrier();
    }
#undef STAGE_A8
#undef STAGE_B8
    // epilogue
    #pragma unroll
    for (int mt = 0; mt < 8; ++mt) {
        #pragma unroll
        for (int nt = 0; nt < 4; ++nt) {
            long row = bm0 + wr * 128 + mt * 16 + quad * 4;
            long col = bn0 + wc * 64 + nt * 16 + l16;
            #pragma unroll
            for (int r = 0; r < 4; ++r)
                C[(row + r) * N + col] = (bf16)acc[mt][nt][r];
        }
    }
}

// ---------------------------------------------------------------- GEMM: C[M,N] = A[M,K] * B[N,K]^T   (bf16 in, fp32 acc, CT out)
#define BM 128
#define BN 128
#define BK 64
template <typename CT>
__global__ __launch_bounds__(256) void gemm_bt(const bf16* __restrict__ A,
                                               const bf16* __restrict__ Bw,
                                               CT* __restrict__ C,
                                               int M, int N, int K) {
    __shared__ __align__(16) bf16 Als[BM * BK];
    __shared__ __align__(16) bf16 Bls[BN * BK];
    int tid  = threadIdx.x;
    int wave = tid >> 6, lane = tid & 63;
    int quad = lane >> 4, l16 = lane & 15;
    int wm = (wave >> 1) << 6;   // 0 / 64
    int wn = (wave & 1) << 6;

    long bm0 = (long)blockIdx.y * BM;
    long bn0 = (long)blockIdx.x * BN;
    const bf16* Ab = A  + bm0 * K;
    const bf16* Bb = Bw + bn0 * K;

    int srow = wave * 32 + (lane >> 3);
    int scol = ((lane & 7) ^ (lane >> 3)) << 3;
    int sdst = (wave * 32 + (lane >> 3)) * BK + ((lane & 7) << 3);

    floatx4 acc[4][4] = {};

    for (int k0 = 0; k0 < K; k0 += BK) {
        #pragma unroll
        for (int i = 0; i < 4; ++i) {
            const bf16* ga = Ab + (long)(srow + i * 8) * K + k0 + scol;
            const bf16* gb = Bb + (long)(srow + i * 8) * K + k0 + scol;
            __builtin_amdgcn_global_load_lds((AS1 const unsigned int*)ga,
                                             (AS3 unsigned int*)(Als + sdst + i * 512), 16, 0, 0);
            __builtin_amdgcn_global_load_lds((AS1 const unsigned int*)gb,
                                             (AS3 unsigned int*)(Bls + sdst + i * 512), 16, 0, 0);
        }
        __syncthreads();
        #pragma unroll
        for (int ks = 0; ks < 2; ++ks) {
            bf16x8 af[4], bfr[4];
            #pragma unroll
            for (int t = 0; t < 4; ++t) {
                int row = wm + t * 16 + l16;
                int g = (ks * 4 + quad) ^ (row & 7);
                af[t] = *(const bf16x8*)(Als + row * BK + (g << 3));
            }
            #pragma unroll
            for (int t = 0; t < 4; ++t) {
                int row = wn + t * 16 + l16;
                int g = (ks * 4 + quad) ^ (row & 7);
                bfr[t] = *(const bf16x8*)(Bls + row * BK + (g << 3));
            }
            #pragma unroll
            for (int mt = 0; mt < 4; ++mt)
                #pragma unroll
                for (int nt = 0; nt < 4; ++nt)
                    acc[mt][nt] = __builtin_amdgcn_mfma_f32_16x16x32_bf16(af[mt], bfr[nt], acc[mt][nt], 0, 0, 0);
        }
        __syncthreads();
    }
    #pragma unroll
    for (int mt = 0; mt < 4; ++mt) {
        #pragma unroll
        for (int nt = 0; nt < 4; ++nt) {
            long row = bm0 + wm + mt * 16 + quad * 4;
            long col = bn0 + wn + nt * 16 + l16;
            #pragma unroll
            for (int r = 0; r < 4; ++r)
                C[(row + r) * N + col] = (CT)acc[mt][nt][r];
        }
    }
}

// ---------------------------------------------------------------- canon_b + RMSNorm + RoPE (token-streaming) + fused V repack
__global__ __launch_bounds__(256, 4) void canon_kernel(const bf16* __restrict__ QKV,
                                                       const float* __restrict__ wq,
                                                       const float* __restrict__ wk,
                                                       const float* __restrict__ wv,
                                                       const float* __restrict__ qnw,
                                                       const float* __restrict__ knw,
                                                       const float* __restrict__ cost,
                                                       const float* __restrict__ sint,
                                                       bf16* __restrict__ qf,
                                                       bf16* __restrict__ kf,
                                                       bf16* __restrict__ vfrag) {
    __shared__ __align__(16) bf16 vtile[32 * 520];   // V blocks only; 520 = 16B-aligned pad
    int tid  = threadIdx.x;
    int wid  = blockIdx.x * 4 + (tid >> 6);
    int lane = tid & 63;
    int b  = wid >> 11;              // 2048 waves per batch
    int g  = (wid >> 8) & 7;         // 512-channel group (0-3 q, 4-5 k, 6-7 v); block-uniform
    int c  = wid & 255;              // 8-token chunk
    int t0 = c << 3;
    int ch = (g << 9) + (lane << 3); // column in QKV row

    const float* wrow; int cw;
    if (g < 4)      { wrow = wq; cw = ch; }
    else if (g < 6) { wrow = wk; cw = ch - 2048; }
    else            { wrow = wv; cw = ch - 3072; }

    float4 w4[8];                    // w4[i] = {w0,w1,w2,w3} of channel ch+i
    #pragma unroll
    for (int j = 0; j < 8; ++j) w4[j] = *(const float4*)(wrow + (cw + j) * 4);

    union U8 { float4 v; bf16 h[8]; };
    const bf16* srcb = QKV + (size_t)((b << 11) + t0) * 4096 + ch;

    // conv window x[t-1], x[t-2], x[t-3]
    float xm1[8], xm2[8], xm3[8];
    if (t0 > 0) {
        U8 u1, u2, u3;
        u1.v = *(const float4*)(srcb - 4096);
        u2.v = *(const float4*)(srcb - 2 * 4096);
        u3.v = *(const float4*)(srcb - 3 * 4096);
        #pragma unroll
        for (int i = 0; i < 8; ++i) {
            xm1[i] = (float)u1.h[i]; xm2[i] = (float)u2.h[i]; xm3[i] = (float)u3.h[i];
        }
    } else {
        #pragma unroll
        for (int i = 0; i < 8; ++i) { xm1[i] = 0.f; xm2[i] = 0.f; xm3[i] = 0.f; }
    }

    float4 nxtv = *(const float4*)(srcb);   // 1-deep token prefetch

    if (g < 6) {
        // ---------------- Q / K: conv + RMSNorm + RoPE -> frag-linear
        int j0   = ch & 127;                                 // d-offset within head
        int head = (g < 4) ? (ch >> 7) : ((ch - 2048) >> 7);
        const float* nw = (g < 4) ? qnw : knw;
        float nwv[8];
        {
            float4 na = *(const float4*)(nw + j0);
            float4 nb = *(const float4*)(nw + j0 + 4);
            #pragma unroll
            for (int i = 0; i < 8; ++i) nwv[i] = (i < 4) ? (&na.x)[i] : (&nb.x)[i - 4];
        }
        int ks = (lane >> 2) & 3, qd = lane & 3;             // frag coords from d-offset
        size_t qkbase = ((size_t)((g < 4 ? (b << 4) : (b << 3)) + head) << 18)
                      + ((size_t)(t0 >> 4) << 11) + ((size_t)ks << 9)
                      + ((size_t)qd << 7) + ((size_t)(t0 & 15) << 3);
        bf16* dstb = (g < 4 ? qf : kf) + qkbase;

        int fi0 = j0 & 63;
        bool neg = (j0 < 64);
        const float* ctp = cost + t0 * 64 + fi0;
        const float* stp = sint + t0 * 64 + fi0;

        #pragma unroll
        for (int tt = 0; tt < 8; ++tt) {
            U8 u; u.v = nxtv;
            if (tt < 7) nxtv = *(const float4*)(srcb + (size_t)(tt + 1) * 4096);
            float cur[8], cv[8];
            #pragma unroll
            for (int i = 0; i < 8; ++i) cur[i] = (float)u.h[i];
            #pragma unroll
            for (int i = 0; i < 8; ++i) {
                float a = fmaf(w4[i].x, cur[i], cur[i]);      // x + w0*x[t]
                a = fmaf(w4[i].y, xm1[i], a);
                a = fmaf(w4[i].z, xm2[i], a);
                cv[i] = fmaf(w4[i].w, xm3[i], a);
                xm3[i] = xm2[i]; xm2[i] = xm1[i]; xm1[i] = cur[i];
            }
            // per-head RMS over 16 lanes (128 ch)
            float ss = 0.f;
            #pragma unroll
            for (int i = 0; i < 8; ++i) ss = fmaf(cv[i], cv[i], ss);
            ss += __shfl_xor(ss, 1); ss += __shfl_xor(ss, 2);
            ss += __shfl_xor(ss, 4); ss += __shfl_xor(ss, 8);
            float r1 = rsqrtf(ss * (1.0f / 128.0f) + 1e-6f);
            float xn[8];
            #pragma unroll
            for (int i = 0; i < 8; ++i) xn[i] = cv[i] * r1 * nwv[i];
            // RoPE
            float4 ca = *(const float4*)(ctp + tt * 64);
            float4 cb = *(const float4*)(ctp + tt * 64 + 4);
            float4 sa = *(const float4*)(stp + tt * 64);
            float4 sb = *(const float4*)(stp + tt * 64 + 4);
            __align__(16) bf16 outv[8];
            #pragma unroll
            for (int i = 0; i < 8; ++i) {
                float xp  = __shfl_xor(xn[i], 8);            // partner channel j +/- 64
                float rot = neg ? -xp : xp;
                float cc = (i < 4) ? (&ca.x)[i] : (&cb.x)[i - 4];
                float sn = (i < 4) ? (&sa.x)[i] : (&sb.x)[i - 4];
                outv[i] = (bf16)fmaf(xn[i], cc, rot * sn);
            }
            *(float4*)(dstb + (tt << 3)) = *(const float4*)outv;
        }
    } else {
        // ---------------- V: conv -> LDS tile -> frag-linear (fused repack)
        int lrow0 = (tid >> 6) << 3;              // wave's 8-row slot in the 32-token tile
        #pragma unroll
        for (int tt = 0; tt < 8; ++tt) {
            U8 u; u.v = nxtv;
            if (tt < 7) nxtv = *(const float4*)(srcb + (size_t)(tt + 1) * 4096);
            float cur[8];
            __align__(16) bf16 outv[8];
            #pragma unroll
            for (int i = 0; i < 8; ++i) cur[i] = (float)u.h[i];
            #pragma unroll
            for (int i = 0; i < 8; ++i) {
                float a = fmaf(w4[i].x, cur[i], cur[i]);
                a = fmaf(w4[i].y, xm1[i], a);
                a = fmaf(w4[i].z, xm2[i], a);
                a = fmaf(w4[i].w, xm3[i], a);
                xm3[i] = xm2[i]; xm2[i] = xm1[i]; xm1[i] = cur[i];
                outv[i] = (bf16)a;
            }
            // wave-contiguous 1KB row write: conflict-free
            *(float4*)(&vtile[(lrow0 + tt) * 520 + (lane << 3)]) = *(const float4*)outv;
        }
        __syncthreads();
        // gather: frag element (t,d): quad=(t>>3)&3, j=t&7, lane=quad*16+(d&15), dnt=d>>4
        int T  = (((blockIdx.x * 4) & 255) << 3); // block's first token (32-aligned)
        int kt = T >> 6, ks = (T >> 5) & 1;
        int hb = (g - 6) << 2;                    // head base 0 / 4
        #pragma unroll
        for (int p = 0; p < 8; ++p) {
            int cidx = tid + p * 256;             // 0..2047 = hd*512 + dnt*64 + lane_c
            int hd  = cidx >> 9;
            int dnt = (cidx >> 6) & 7;
            int lc  = cidx & 63;
            int quad = lc >> 4, l16 = lc & 15;
            int scol = hd * 128 + dnt * 16 + l16;
            __align__(16) bf16 outv[8];
            #pragma unroll
            for (int j = 0; j < 8; ++j)
                outv[j] = vtile[(quad * 8 + j) * 520 + scol];
            size_t off = (((size_t)(b * 8 + hb + hd) * 32 + kt) << 13)
                       + ((size_t)ks << 12) + ((size_t)dnt << 9) + ((size_t)lc << 3);
            *(float4*)(vfrag + off) = *(const float4*)outv;
        }
    }
}

// ---------------------------------------------------------------- flash attention (causal, GQA)
__global__ __launch_bounds__(256) void flash_attn(const bf16* __restrict__ qf,
                                                  const bf16* __restrict__ kf,
                                                  const bf16* __restrict__ vfrag,
                                                  bf16* __restrict__ attn) {
    __shared__ __align__(16) bf16 Kls[2][8192];   // 64 keys x 128 d, frag-linear
    __shared__ __align__(16) bf16 Vls[2][8192];
    __shared__ __align__(16) bf16 Pls[4][16][72];
    int lid  = blockIdx.x;                         // 0..1023
    int pair = lid & 15;                           // (b*8+kvh) -> stable XCD via lid%8
    int b    = pair >> 3, kvh = pair & 7;
    int inner = lid >> 4;                          // 0..63
    int qt   = 31 - (inner >> 1);                  // longest q-tiles first
    int h    = kvh * 2 + (inner & 1);
    int tid = threadIdx.x, wave = tid >> 6, lane = tid & 63;
    int quad = lane >> 4, l16 = lane & 15;
    int qrow0 = (qt << 6) + (wave << 4);

    const bf16* kfp = kf    + (((size_t)b * KVH_ + kvh) << 18);   // 32 kt * 8192
    const bf16* vfp = vfrag + (((size_t)b * KVH_ + kvh) << 18);
    const bf16* qfp = qf    + ((((size_t)(b * H_ + h) * 128 + (qt << 2) + wave)) << 11);

    bf16x8 aq[4];
    #pragma unroll
    for (int ks = 0; ks < 4; ++ks)
        aq[ks] = *(const bf16x8*)(qfp + (ks << 9) + (lane << 3));

    floatx4 o[8] = {};
    float l_i[4] = {0.f, 0.f, 0.f, 0.f};
    const float scl2 = 0.08838834764831845f * 1.4426950408889634f;  // scale*log2(e)

    int ktiles = qt + 1;
    int eo = tid << 3;                 // stage offset: tid*8 elems (lane*16B within wave)

    // prologue: issue stage of tile 0 into buf 0
    #pragma unroll
    for (int i = 0; i < 4; ++i) {
        __builtin_amdgcn_global_load_lds((AS1 const unsigned int*)(kfp + eo + (i << 11)),
                                         (AS3 unsigned int*)(&Kls[0][0] + eo + (i << 11)), 16, 0, 0);
        __builtin_amdgcn_global_load_lds((AS1 const unsigned int*)(vfp + eo + (i << 11)),
                                         (AS3 unsigned int*)(&Vls[0][0] + eo + (i << 11)), 16, 0, 0);
    }

    int cur = 0;
    for (int kt = 0; kt < ktiles; ++kt) {
        __syncthreads();   // drains the stage of buf[cur]; fences prev compute on buf[cur^1]
        if (kt + 1 < ktiles) {
            const bf16* ksrc = kfp + (((size_t)(kt + 1)) << 13) + eo;
            const bf16* vsrc = vfp + (((size_t)(kt + 1)) << 13) + eo;
            bf16* kd = &Kls[cur ^ 1][0] + eo;
            bf16* vd = &Vls[cur ^ 1][0] + eo;
            #pragma unroll
            for (int i = 0; i < 4; ++i) {
                __builtin_amdgcn_global_load_lds((AS1 const unsigned int*)(ksrc + (i << 11)),
                                                 (AS3 unsigned int*)(kd + (i << 11)), 16, 0, 0);
                __builtin_amdgcn_global_load_lds((AS1 const unsigned int*)(vsrc + (i << 11)),
                                                 (AS3 unsigned int*)(vd + (i << 11)), 16, 0, 0);
            }
        }
        const bf16* Kb = &Kls[cur][0];
        const bf16* Vb = &Vls[cur][0];
        // S = Q K^T (K frags from LDS: contiguous 1KB per frag, conflict-free)
        floatx4 sc[4] = {};
        #pragma unroll
        for (int nt = 0; nt < 4; ++nt) {
            #pragma unroll
            for (int ks = 0; ks < 4; ++ks) {
                bf16x8 kb8 = *(const bf16x8*)(Kb + ((nt * 4 + ks) << 9) + (lane << 3));
                sc[nt] = __builtin_amdgcn_mfma_f32_16x16x32_bf16(aq[ks], kb8, sc[nt], 0, 0, 0);
            }
        }
        // p = exp2(s*scl2); mask only on the final (diagonal) tile
        int qr0 = qrow0 + (quad << 2);
        int kb = kt << 6;
        if (kt == ktiles - 1) {
            #pragma unroll
            for (int nt = 0; nt < 4; ++nt) {
                int key = kb + nt * 16 + l16;
                #pragma unroll
                for (int r = 0; r < 4; ++r) {
                    float pv = exp2f(sc[nt][r] * scl2);
                    pv = (key <= qr0 + r) ? pv : 0.f;
                    l_i[r] += pv;
                    Pls[wave][(quad << 2) + r][nt * 16 + l16] = (bf16)pv;
                }
            }
        } else {
            #pragma unroll
            for (int nt = 0; nt < 4; ++nt) {
                #pragma unroll
                for (int r = 0; r < 4; ++r) {
                    float pv = exp2f(sc[nt][r] * scl2);
                    l_i[r] += pv;
                    Pls[wave][(quad << 2) + r][nt * 16 + l16] = (bf16)pv;
                }
            }
        }
        // O += P V (V frags from LDS)
        {
            bf16x8 pa = *(const bf16x8*)(&Pls[wave][l16][(quad << 3)]);
            #pragma unroll
            for (int dnt = 0; dnt < 8; ++dnt) {
                bf16x8 vb = *(const bf16x8*)(Vb + ((size_t)dnt << 9) + (lane << 3));
                o[dnt] = __builtin_amdgcn_mfma_f32_16x16x32_bf16(pa, vb, o[dnt], 0, 0, 0);
            }
            bf16x8 pb = *(const bf16x8*)(&Pls[wave][l16][32 + (quad << 3)]);
            #pragma unroll
            for (int dnt = 0; dnt < 8; ++dnt) {
                bf16x8 vb = *(const bf16x8*)(Vb + ((size_t)(8 + dnt) << 9) + (lane << 3));
                o[dnt] = __builtin_amdgcn_mfma_f32_16x16x32_bf16(pb, vb, o[dnt], 0, 0, 0);
            }
        }
        cur ^= 1;
    }
    // epilogue
    #pragma unroll
    for (int r = 0; r < 4; ++r) {
        float l = l_i[r];
        l += __shfl_xor(l, 1); l += __shfl_xor(l, 2);
        l += __shfl_xor(l, 4); l += __shfl_xor(l, 8);
        l_i[r] = 1.0f / l;
    }
    #pragma unroll
    for (int dnt = 0; dnt < 8; ++dnt) {
        #pragma unroll
        for (int r = 0; r < 4; ++r) {
            size_t row = (size_t)b * S_ + qrow0 + (quad << 2) + r;
            attn[row * D_ + h * DH_ + dnt * 16 + l16] = (bf16)(o[dnt][r] * l_i[r]);
        }
    }
}

// ---------------------------------------------------------------- launch
extern "C" void kernel_launch(void* const* d_in, const int* in_sizes, int n_in,
                              void* d_out, int out_size, void* d_ws, size_t ws_size,
                              hipStream_t stream) {
    const float* hidden = (const float*)d_in[0];
    const float* Wq  = (const float*)d_in[1];
    const float* Wk  = (const float*)d_in[2];
    const float* Wv  = (const float*)d_in[3];
    const float* Wo  = (const float*)d_in[4];
    const float* cqw = (const float*)d_in[5];
    const float* ckw = (const float*)d_in[6];
    const float* cvw = (const float*)d_in[7];
    const float* qnw = (const float*)d_in[8];
    const float* knw = (const float*)d_in[9];

    char* p = (char*)d_ws;
    auto alloc = [&](size_t bytes) { char* r = p; p += (bytes + 255) & ~(size_t)255; return r; };
    bf16*  X    = (bf16*)alloc((size_t)M_ * D_ * 2);
    bf16*  Wcat = (bf16*)alloc((size_t)NQKV_ * D_ * 2);
    bf16*  Wob  = (bf16*)alloc((size_t)D_ * D_ * 2);
    bf16*  QKV  = (bf16*)alloc((size_t)M_ * NQKV_ * 2);
    bf16*  qfb  = (bf16*)alloc((size_t)B_ * H_ * S_ * DH_ * 2);   // frag-linear Q
    bf16*  kfb  = (bf16*)alloc((size_t)B_ * KVH_ * S_ * DH_ * 2); // frag-linear K
    bf16*  vfr  = (bf16*)alloc((size_t)B_ * KVH_ * S_ * DH_ * 2); // frag-linear V
    float* cost = (float*)alloc((size_t)S_ * 64 * 4);
    float* sint = (float*)alloc((size_t)S_ * 64 * 4);
    bf16*  attnb = QKV;   // QKV dead after canon_kernel

    prep_kernel<<<20992, 256, 0, stream>>>(hidden, Wq, Wk, Wv, Wo, X, Wcat, Wob, cost, sint);
    gemm_bt8<<<(M_ / 256) * (NQKV_ / 256), 512, 0, stream>>>(X, Wcat, QKV, M_, NQKV_, D_);
    canon_kernel<<<1024, 256, 0, stream>>>(QKV, cqw, ckw, cvw, qnw, knw, cost, sint, qfb, kfb, vfr);
    flash_attn<<<1024, 256, 0, stream>>>(qfb, kfb, vfr, attnb);
    gemm_bt<float><<<dim3(D_ / BN, M_ / BM), 256, 0, stream>>>(attnb, Wob, (float*)d_out, M_, D_, D_);
}

// Round 9
// 338.619 us; speedup vs baseline: 1.8465x; 1.0178x over previous
//
#include <hip/hip_runtime.h>
#include <hip/hip_bf16.h>

typedef __bf16 bf16;
typedef __bf16 bf16x8 __attribute__((ext_vector_type(8)));
typedef float  floatx4 __attribute__((ext_vector_type(4)));

#define AS1 __attribute__((address_space(1)))
#define AS3 __attribute__((address_space(3)))

#define B_    2
#define S_    2048
#define D_    2048
#define H_    16
#define KVH_  8
#define DH_   128
#define M_    4096      // B_*S_
#define NQKV_ 4096      // D_ + 2*KVH_*DH_

// ---------------------------------------------------------------- fused prep: all fp32->bf16 casts + RoPE tables
__global__ __launch_bounds__(256) void prep_kernel(const float* __restrict__ hidden,
                                                   const float* __restrict__ Wq,
                                                   const float* __restrict__ Wk,
                                                   const float* __restrict__ Wv,
                                                   const float* __restrict__ Wo,
                                                   bf16* __restrict__ X,
                                                   bf16* __restrict__ Wcat,
                                                   bf16* __restrict__ Wob,
                                                   float* __restrict__ cost,
                                                   float* __restrict__ sint) {
    size_t u = (size_t)blockIdx.x * 256 + threadIdx.x;
    if (u < 5242880) {
        const float* src; bf16* dst; size_t off;
        if (u < 2097152)      { src = hidden; dst = X;              off = u; }
        else if (u < 3145728) { src = Wq;     dst = Wcat;           off = u - 2097152; }
        else if (u < 3670016) { src = Wk;     dst = Wcat + 4194304; off = u - 3145728; }
        else if (u < 4194304) { src = Wv;     dst = Wcat + 6291456; off = u - 3670016; }
        else                  { src = Wo;     dst = Wob;            off = u - 4194304; }
        float4 v = *(const float4*)(src + off * 4);
        union { bf16 h[4]; double d; } uu;
        uu.h[0] = (bf16)v.x; uu.h[1] = (bf16)v.y; uu.h[2] = (bf16)v.z; uu.h[3] = (bf16)v.w;
        *(double*)(dst + off * 4) = uu.d;
    } else {
        int r = (int)(u - 5242880);              // 0..131071
        int t = r >> 6, fi = r & 63;
        float inv = expf(-9.210340371976184f * (float)fi * (1.0f / 64.0f)); // 10000^(-fi/64)
        float ang = (float)t * inv;
        cost[r] = cosf(ang);
        sint[r] = sinf(ang);
    }
}

// ---------------------------------------------------------------- 256x256 GEMM: counted vmcnt, 4-deep LDS ring, compiler-scheduled
// C[M,N] = A[M,K] * B[N,K]^T, bf16 in/out, fp32 acc. BK=32, 8 waves (2Mx4N),
// per-wave 128x64 output. LDS: 4 bufs x (A 16KB + B 16KB) = 128 KiB -> 3-tile
// lookahead, per-tile gate vmcnt(8) (never 0 in main loop). ONE raw s_barrier
// per K-tile, NO lgkmcnt(0) drain, NO sched_barrier: ds_reads are plain C++
// so the compiler inserts fine-grained per-MFMA lgkmcnt (each MFMA starts as
// soon as ITS fragments land), overlapping read-drain with matrix work and
// staggering waves on the LDS pipe. (R8 post-mortem: explicit full drain +
// sched pin serialized [reads][MFMA] in lockstep -> 1489 cyc/tile vs ~310
// of work; R7<->R8 null showed barrier count wasn't the lever.)
// Sync ledger: RAW - reads of buf[u&3] gated by tile u-1's vmcnt(8) (oldest
// 4 = tile u's stages) + closing barrier. WAR - stage of buf[(u+3)&3] issues
// after tile u-1's closing barrier; its readers (tile u-1) consumed all reads
// before that barrier (every read feeds an MFMA before it). Gate ladder
// 8 -> 4 (u==NT-3) -> 0. Read swizzle: chunk slot = quad ^ ((l16^(l16>>2))&3),
// lane-constant; staged via inverse-permuted global source + linear dest.
__global__ __launch_bounds__(512, 2) void gemm_bt8(const bf16* __restrict__ A,
                                                   const bf16* __restrict__ Bw,
                                                   bf16* __restrict__ C,
                                                   int M, int N, int K) {
    __shared__ __align__(16) bf16 Als[4][256 * 32];
    __shared__ __align__(16) bf16 Bls[4][256 * 32];
    int tid  = threadIdx.x;
    int wave = tid >> 6, lane = tid & 63;
    int quad = lane >> 4, l16 = lane & 15;
    int wr = wave >> 2, wc = wave & 3;            // 2 x 4 wave grid

    int nbx = N >> 8;
    int wg  = (blockIdx.x & 7) * ((int)gridDim.x >> 3) + (blockIdx.x >> 3); // bijective (grid%8==0)
    int by  = wg / nbx, bx = wg % nbx;
    long bm0 = (long)by << 8, bn0 = (long)bx << 8;

    // read-side swizzle slot (lane-constant: row&3 == l16&3, (row>>2)&3 == (l16>>2)&3 for 16-aligned bases)
    int slot8 = ((quad ^ ((l16 ^ (l16 >> 2)) & 3)) << 3);

    // stage addressing: chunk c = tid (+512); row=c>>2, lds slot=c&3, src chunk=(c&3)^xr(row)
    int srow   = tid >> 2;                        // 0..127 (load1: +128, same xr)
    int schunk = (tid & 3) ^ ((srow ^ (srow >> 2)) & 3);
    const bf16* Asrc = A  + (bm0 + srow) * K + schunk * 8;
    const bf16* Bsrc = Bw + (bn0 + srow) * K + schunk * 8;
    size_t ldoff = (size_t)128 * K;               // second-load source row offset

    floatx4 acc[8][4] = {};
    int NT = K >> 5;

#define STAGE_A8(t) { int d_ = (t) & 3; long k0_ = (long)(t) << 5;                                   \
    __builtin_amdgcn_global_load_lds((AS1 const unsigned int*)(Asrc + k0_),                          \
                                     (AS3 unsigned int*)(&Als[d_][0] + tid * 8), 16, 0, 0);          \
    __builtin_amdgcn_global_load_lds((AS1 const unsigned int*)(Asrc + ldoff + k0_),                  \
                                     (AS3 unsigned int*)(&Als[d_][0] + tid * 8 + 4096), 16, 0, 0); }
#define STAGE_B8(t) { int d_ = (t) & 3; long k0_ = (long)(t) << 5;                                   \
    __builtin_amdgcn_global_load_lds((AS1 const unsigned int*)(Bsrc + k0_),                          \
                                     (AS3 unsigned int*)(&Bls[d_][0] + tid * 8), 16, 0, 0);          \
    __builtin_amdgcn_global_load_lds((AS1 const unsigned int*)(Bsrc + ldoff + k0_),                  \
                                     (AS3 unsigned int*)(&Bls[d_][0] + tid * 8 + 4096), 16, 0, 0); }

    // prologue: stage tiles 0,1,2 in order; gate tile 0 (8 newest may stay in flight)
    STAGE_A8(0); STAGE_B8(0);
    STAGE_A8(1); STAGE_B8(1);
    STAGE_A8(2); STAGE_B8(2);
    asm volatile("s_waitcnt vmcnt(8)" ::: "memory");
    __builtin_amdgcn_s_barrier();

    for (int u = 0; u < NT; ++u) {
        const bf16* Ab = &Als[u & 3][0];
        const bf16* Bb = &Bls[u & 3][0];
        bf16x8 af[8], bfr[4];
        #pragma unroll
        for (int mt = 0; mt < 8; ++mt) {
            int row = wr * 128 + mt * 16 + l16;
            af[mt] = *(const bf16x8*)(Ab + row * 32 + slot8);
        }
        #pragma unroll
        for (int nt = 0; nt < 4; ++nt) {
            int col = wc * 64 + nt * 16 + l16;
            bfr[nt] = *(const bf16x8*)(Bb + col * 32 + slot8);
        }
        if (u + 3 < NT) { STAGE_A8(u + 3); STAGE_B8(u + 3); }
        // MFMAs: compiler inserts per-MFMA lgkmcnt -> overlaps with read drain
        #pragma unroll
        for (int mt = 0; mt < 8; ++mt)
            #pragma unroll
            for (int nt = 0; nt < 4; ++nt)
                acc[mt][nt] = __builtin_amdgcn_mfma_f32_16x16x32_bf16(af[mt], bfr[nt], acc[mt][nt], 0, 0, 0);
        if (u < NT - 3)       { asm volatile("s_waitcnt vmcnt(8)" ::: "memory"); }
        else if (u == NT - 3) { asm volatile("s_waitcnt vmcnt(4)" ::: "memory"); }
        else                  { asm volatile("s_waitcnt vmcnt(0)" ::: "memory"); }
        __builtin_amdgcn_s_barrier();
    }
#undef STAGE_A8
#undef STAGE_B8
    // epilogue
    #pragma unroll
    for (int mt = 0; mt < 8; ++mt) {
        #pragma unroll
        for (int nt = 0; nt < 4; ++nt) {
            long row = bm0 + wr * 128 + mt * 16 + quad * 4;
            long col = bn0 + wc * 64 + nt * 16 + l16;
            #pragma unroll
            for (int r = 0; r < 4; ++r)
                C[(row + r) * N + col] = (bf16)acc[mt][nt][r];
        }
    }
}

// ---------------------------------------------------------------- GEMM: C[M,N] = A[M,K] * B[N,K]^T   (bf16 in, fp32 acc, CT out)
#define BM 128
#define BN 128
#define BK 64
template <typename CT>
__global__ __launch_bounds__(256) void gemm_bt(const bf16* __restrict__ A,
                                               const bf16* __restrict__ Bw,
                                               CT* __restrict__ C,
                                               int M, int N, int K) {
    __shared__ __align__(16) bf16 Als[BM * BK];
    __shared__ __align__(16) bf16 Bls[BN * BK];
    int tid  = threadIdx.x;
    int wave = tid >> 6, lane = tid & 63;
    int quad = lane >> 4, l16 = lane & 15;
    int wm = (wave >> 1) << 6;   // 0 / 64
    int wn = (wave & 1) << 6;

    long bm0 = (long)blockIdx.y * BM;
    long bn0 = (long)blockIdx.x * BN;
    const bf16* Ab = A  + bm0 * K;
    const bf16* Bb = Bw + bn0 * K;

    int srow = wave * 32 + (lane >> 3);
    int scol = ((lane & 7) ^ (lane >> 3)) << 3;
    int sdst = (wave * 32 + (lane >> 3)) * BK + ((lane & 7) << 3);

    floatx4 acc[4][4] = {};

    for (int k0 = 0; k0 < K; k0 += BK) {
        #pragma unroll
        for (int i = 0; i < 4; ++i) {
            const bf16* ga = Ab + (long)(srow + i * 8) * K + k0 + scol;
            const bf16* gb = Bb + (long)(srow + i * 8) * K + k0 + scol;
            __builtin_amdgcn_global_load_lds((AS1 const unsigned int*)ga,
                                             (AS3 unsigned int*)(Als + sdst + i * 512), 16, 0, 0);
            __builtin_amdgcn_global_load_lds((AS1 const unsigned int*)gb,
                                             (AS3 unsigned int*)(Bls + sdst + i * 512), 16, 0, 0);
        }
        __syncthreads();
        #pragma unroll
        for (int ks = 0; ks < 2; ++ks) {
            bf16x8 af[4], bfr[4];
            #pragma unroll
            for (int t = 0; t < 4; ++t) {
                int row = wm + t * 16 + l16;
                int g = (ks * 4 + quad) ^ (row & 7);
                af[t] = *(const bf16x8*)(Als + row * BK + (g << 3));
            }
            #pragma unroll
            for (int t = 0; t < 4; ++t) {
                int row = wn + t * 16 + l16;
                int g = (ks * 4 + quad) ^ (row & 7);
                bfr[t] = *(const bf16x8*)(Bls + row * BK + (g << 3));
            }
            #pragma unroll
            for (int mt = 0; mt < 4; ++mt)
                #pragma unroll
                for (int nt = 0; nt < 4; ++nt)
                    acc[mt][nt] = __builtin_amdgcn_mfma_f32_16x16x32_bf16(af[mt], bfr[nt], acc[mt][nt], 0, 0, 0);
        }
        __syncthreads();
    }
    #pragma unroll
    for (int mt = 0; mt < 4; ++mt) {
        #pragma unroll
        for (int nt = 0; nt < 4; ++nt) {
            long row = bm0 + wm + mt * 16 + quad * 4;
            long col = bn0 + wn + nt * 16 + l16;
            #pragma unroll
            for (int r = 0; r < 4; ++r)
                C[(row + r) * N + col] = (CT)acc[mt][nt][r];
        }
    }
}

// ---------------------------------------------------------------- canon_b + RMSNorm + RoPE (token-streaming) + fused V repack
__global__ __launch_bounds__(256, 4) void canon_kernel(const bf16* __restrict__ QKV,
                                                       const float* __restrict__ wq,
                                                       const float* __restrict__ wk,
                                                       const float* __restrict__ wv,
                                                       const float* __restrict__ qnw,
                                                       const float* __restrict__ knw,
                                                       const float* __restrict__ cost,
                                                       const float* __restrict__ sint,
                                                       bf16* __restrict__ qf,
                                                       bf16* __restrict__ kf,
                                                       bf16* __restrict__ vfrag) {
    __shared__ __align__(16) bf16 vtile[32 * 520];   // V blocks only; 520 = 16B-aligned pad
    int tid  = threadIdx.x;
    int wid  = blockIdx.x * 4 + (tid >> 6);
    int lane = tid & 63;
    int b  = wid >> 11;              // 2048 waves per batch
    int g  = (wid >> 8) & 7;         // 512-channel group (0-3 q, 4-5 k, 6-7 v); block-uniform
    int c  = wid & 255;              // 8-token chunk
    int t0 = c << 3;
    int ch = (g << 9) + (lane << 3); // column in QKV row

    const float* wrow; int cw;
    if (g < 4)      { wrow = wq; cw = ch; }
    else if (g < 6) { wrow = wk; cw = ch - 2048; }
    else            { wrow = wv; cw = ch - 3072; }

    float4 w4[8];                    // w4[i] = {w0,w1,w2,w3} of channel ch+i
    #pragma unroll
    for (int j = 0; j < 8; ++j) w4[j] = *(const float4*)(wrow + (cw + j) * 4);

    union U8 { float4 v; bf16 h[8]; };
    const bf16* srcb = QKV + (size_t)((b << 11) + t0) * 4096 + ch;

    // conv window x[t-1], x[t-2], x[t-3]
    float xm1[8], xm2[8], xm3[8];
    if (t0 > 0) {
        U8 u1, u2, u3;
        u1.v = *(const float4*)(srcb - 4096);
        u2.v = *(const float4*)(srcb - 2 * 4096);
        u3.v = *(const float4*)(srcb - 3 * 4096);
        #pragma unroll
        for (int i = 0; i < 8; ++i) {
            xm1[i] = (float)u1.h[i]; xm2[i] = (float)u2.h[i]; xm3[i] = (float)u3.h[i];
        }
    } else {
        #pragma unroll
        for (int i = 0; i < 8; ++i) { xm1[i] = 0.f; xm2[i] = 0.f; xm3[i] = 0.f; }
    }

    float4 nxtv = *(const float4*)(srcb);   // 1-deep token prefetch

    if (g < 6) {
        // ---------------- Q / K: conv + RMSNorm + RoPE -> frag-linear
        int j0   = ch & 127;                                 // d-offset within head
        int head = (g < 4) ? (ch >> 7) : ((ch - 2048) >> 7);
        const float* nw = (g < 4) ? qnw : knw;
        float nwv[8];
        {
            float4 na = *(const float4*)(nw + j0);
            float4 nb = *(const float4*)(nw + j0 + 4);
            #pragma unroll
            for (int i = 0; i < 8; ++i) nwv[i] = (i < 4) ? (&na.x)[i] : (&nb.x)[i - 4];
        }
        int ks = (lane >> 2) & 3, qd = lane & 3;             // frag coords from d-offset
        size_t qkbase = ((size_t)((g < 4 ? (b << 4) : (b << 3)) + head) << 18)
                      + ((size_t)(t0 >> 4) << 11) + ((size_t)ks << 9)
                      + ((size_t)qd << 7) + ((size_t)(t0 & 15) << 3);
        bf16* dstb = (g < 4 ? qf : kf) + qkbase;

        int fi0 = j0 & 63;
        bool neg = (j0 < 64);
        const float* ctp = cost + t0 * 64 + fi0;
        const float* stp = sint + t0 * 64 + fi0;

        #pragma unroll
        for (int tt = 0; tt < 8; ++tt) {
            U8 u; u.v = nxtv;
            if (tt < 7) nxtv = *(const float4*)(srcb + (size_t)(tt + 1) * 4096);
            float cur[8], cv[8];
            #pragma unroll
            for (int i = 0; i < 8; ++i) cur[i] = (float)u.h[i];
            #pragma unroll
            for (int i = 0; i < 8; ++i) {
                float a = fmaf(w4[i].x, cur[i], cur[i]);      // x + w0*x[t]
                a = fmaf(w4[i].y, xm1[i], a);
                a = fmaf(w4[i].z, xm2[i], a);
                cv[i] = fmaf(w4[i].w, xm3[i], a);
                xm3[i] = xm2[i]; xm2[i] = xm1[i]; xm1[i] = cur[i];
            }
            // per-head RMS over 16 lanes (128 ch)
            float ss = 0.f;
            #pragma unroll
            for (int i = 0; i < 8; ++i) ss = fmaf(cv[i], cv[i], ss);
            ss += __shfl_xor(ss, 1); ss += __shfl_xor(ss, 2);
            ss += __shfl_xor(ss, 4); ss += __shfl_xor(ss, 8);
            float r1 = rsqrtf(ss * (1.0f / 128.0f) + 1e-6f);
            float xn[8];
            #pragma unroll
            for (int i = 0; i < 8; ++i) xn[i] = cv[i] * r1 * nwv[i];
            // RoPE
            float4 ca = *(const float4*)(ctp + tt * 64);
            float4 cb = *(const float4*)(ctp + tt * 64 + 4);
            float4 sa = *(const float4*)(stp + tt * 64);
            float4 sb = *(const float4*)(stp + tt * 64 + 4);
            __align__(16) bf16 outv[8];
            #pragma unroll
            for (int i = 0; i < 8; ++i) {
                float xp  = __shfl_xor(xn[i], 8);            // partner channel j +/- 64
                float rot = neg ? -xp : xp;
                float cc = (i < 4) ? (&ca.x)[i] : (&cb.x)[i - 4];
                float sn = (i < 4) ? (&sa.x)[i] : (&sb.x)[i - 4];
                outv[i] = (bf16)fmaf(xn[i], cc, rot * sn);
            }
            *(float4*)(dstb + (tt << 3)) = *(const float4*)outv;
        }
    } else {
        // ---------------- V: conv -> LDS tile -> frag-linear (fused repack)
        int lrow0 = (tid >> 6) << 3;              // wave's 8-row slot in the 32-token tile
        #pragma unroll
        for (int tt = 0; tt < 8; ++tt) {
            U8 u; u.v = nxtv;
            if (tt < 7) nxtv = *(const float4*)(srcb + (size_t)(tt + 1) * 4096);
            float cur[8];
            __align__(16) bf16 outv[8];
            #pragma unroll
            for (int i = 0; i < 8; ++i) cur[i] = (float)u.h[i];
            #pragma unroll
            for (int i = 0; i < 8; ++i) {
                float a = fmaf(w4[i].x, cur[i], cur[i]);
                a = fmaf(w4[i].y, xm1[i], a);
                a = fmaf(w4[i].z, xm2[i], a);
                a = fmaf(w4[i].w, xm3[i], a);
                xm3[i] = xm2[i]; xm2[i] = xm1[i]; xm1[i] = cur[i];
                outv[i] = (bf16)a;
            }
            // wave-contiguous 1KB row write: conflict-free
            *(float4*)(&vtile[(lrow0 + tt) * 520 + (lane << 3)]) = *(const float4*)outv;
        }
        __syncthreads();
        // gather: frag element (t,d): quad=(t>>3)&3, j=t&7, lane=quad*16+(d&15), dnt=d>>4
        int T  = (((blockIdx.x * 4) & 255) << 3); // block's first token (32-aligned)
        int kt = T >> 6, ks = (T >> 5) & 1;
        int hb = (g - 6) << 2;                    // head base 0 / 4
        #pragma unroll
        for (int p = 0; p < 8; ++p) {
            int cidx = tid + p * 256;             // 0..2047 = hd*512 + dnt*64 + lane_c
            int hd  = cidx >> 9;
            int dnt = (cidx >> 6) & 7;
            int lc  = cidx & 63;
            int quad = lc >> 4, l16 = lc & 15;
            int scol = hd * 128 + dnt * 16 + l16;
            __align__(16) bf16 outv[8];
            #pragma unroll
            for (int j = 0; j < 8; ++j)
                outv[j] = vtile[(quad * 8 + j) * 520 + scol];
            size_t off = (((size_t)(b * 8 + hb + hd) * 32 + kt) << 13)
                       + ((size_t)ks << 12) + ((size_t)dnt << 9) + ((size_t)lc << 3);
            *(float4*)(vfrag + off) = *(const float4*)outv;
        }
    }
}

// ---------------------------------------------------------------- flash attention (causal, GQA)
__global__ __launch_bounds__(256) void flash_attn(const bf16* __restrict__ qf,
                                                  const bf16* __restrict__ kf,
                                                  const bf16* __restrict__ vfrag,
                                                  bf16* __restrict__ attn) {
    __shared__ __align__(16) bf16 Kls[2][8192];   // 64 keys x 128 d, frag-linear
    __shared__ __align__(16) bf16 Vls[2][8192];
    __shared__ __align__(16) bf16 Pls[4][16][72];
    int lid  = blockIdx.x;                         // 0..1023
    int pair = lid & 15;                           // (b*8+kvh) -> stable XCD via lid%8
    int b    = pair >> 3, kvh = pair & 7;
    int inner = lid >> 4;                          // 0..63
    int qt   = 31 - (inner >> 1);                  // longest q-tiles first
    int h    = kvh * 2 + (inner & 1);
    int tid = threadIdx.x, wave = tid >> 6, lane = tid & 63;
    int quad = lane >> 4, l16 = lane & 15;
    int qrow0 = (qt << 6) + (wave << 4);

    const bf16* kfp = kf    + (((size_t)b * KVH_ + kvh) << 18);   // 32 kt * 8192
    const bf16* vfp = vfrag + (((size_t)b * KVH_ + kvh) << 18);
    const bf16* qfp = qf    + ((((size_t)(b * H_ + h) * 128 + (qt << 2) + wave)) << 11);

    bf16x8 aq[4];
    #pragma unroll
    for (int ks = 0; ks < 4; ++ks)
        aq[ks] = *(const bf16x8*)(qfp + (ks << 9) + (lane << 3));

    floatx4 o[8] = {};
    float l_i[4] = {0.f, 0.f, 0.f, 0.f};
    const float scl2 = 0.08838834764831845f * 1.4426950408889634f;  // scale*log2(e)

    int ktiles = qt + 1;
    int eo = tid << 3;                 // stage offset: tid*8 elems (lane*16B within wave)

    // prologue: issue stage of tile 0 into buf 0
    #pragma unroll
    for (int i = 0; i < 4; ++i) {
        __builtin_amdgcn_global_load_lds((AS1 const unsigned int*)(kfp + eo + (i << 11)),
                                         (AS3 unsigned int*)(&Kls[0][0] + eo + (i << 11)), 16, 0, 0);
        __builtin_amdgcn_global_load_lds((AS1 const unsigned int*)(vfp + eo + (i << 11)),
                                         (AS3 unsigned int*)(&Vls[0][0] + eo + (i << 11)), 16, 0, 0);
    }

    int cur = 0;
    for (int kt = 0; kt < ktiles; ++kt) {
        __syncthreads();   // drains the stage of buf[cur]; fences prev compute on buf[cur^1]
        if (kt + 1 < ktiles) {
            const bf16* ksrc = kfp + (((size_t)(kt + 1)) << 13) + eo;
            const bf16* vsrc = vfp + (((size_t)(kt + 1)) << 13) + eo;
            bf16* kd = &Kls[cur ^ 1][0] + eo;
            bf16* vd = &Vls[cur ^ 1][0] + eo;
            #pragma unroll
            for (int i = 0; i < 4; ++i) {
                __builtin_amdgcn_global_load_lds((AS1 const unsigned int*)(ksrc + (i << 11)),
                                                 (AS3 unsigned int*)(kd + (i << 11)), 16, 0, 0);
                __builtin_amdgcn_global_load_lds((AS1 const unsigned int*)(vsrc + (i << 11)),
                                                 (AS3 unsigned int*)(vd + (i << 11)), 16, 0, 0);
            }
        }
        const bf16* Kb = &Kls[cur][0];
        const bf16* Vb = &Vls[cur][0];
        // S = Q K^T (K frags from LDS: contiguous 1KB per frag, conflict-free)
        floatx4 sc[4] = {};
        #pragma unroll
        for (int nt = 0; nt < 4; ++nt) {
            #pragma unroll
            for (int ks = 0; ks < 4; ++ks) {
                bf16x8 kb8 = *(const bf16x8*)(Kb + ((nt * 4 + ks) << 9) + (lane << 3));
                sc[nt] = __builtin_amdgcn_mfma_f32_16x16x32_bf16(aq[ks], kb8, sc[nt], 0, 0, 0);
            }
        }
        // p = exp2(s*scl2); mask only on the final (diagonal) tile
        int qr0 = qrow0 + (quad << 2);
        int kb = kt << 6;
        if (kt == ktiles - 1) {
            #pragma unroll
            for (int nt = 0; nt < 4; ++nt) {
                int key = kb + nt * 16 + l16;
                #pragma unroll
                for (int r = 0; r < 4; ++r) {
                    float pv = exp2f(sc[nt][r] * scl2);
                    pv = (key <= qr0 + r) ? pv : 0.f;
                    l_i[r] += pv;
                    Pls[wave][(quad << 2) + r][nt * 16 + l16] = (bf16)pv;
                }
            }
        } else {
            #pragma unroll
            for (int nt = 0; nt < 4; ++nt) {
                #pragma unroll
                for (int r = 0; r < 4; ++r) {
                    float pv = exp2f(sc[nt][r] * scl2);
                    l_i[r] += pv;
                    Pls[wave][(quad << 2) + r][nt * 16 + l16] = (bf16)pv;
                }
            }
        }
        // O += P V (V frags from LDS)
        {
            bf16x8 pa = *(const bf16x8*)(&Pls[wave][l16][(quad << 3)]);
            #pragma unroll
            for (int dnt = 0; dnt < 8; ++dnt) {
                bf16x8 vb = *(const bf16x8*)(Vb + ((size_t)dnt << 9) + (lane << 3));
                o[dnt] = __builtin_amdgcn_mfma_f32_16x16x32_bf16(pa, vb, o[dnt], 0, 0, 0);
            }
            bf16x8 pb = *(const bf16x8*)(&Pls[wave][l16][32 + (quad << 3)]);
            #pragma unroll
            for (int dnt = 0; dnt < 8; ++dnt) {
                bf16x8 vb = *(const bf16x8*)(Vb + ((size_t)(8 + dnt) << 9) + (lane << 3));
                o[dnt] = __builtin_amdgcn_mfma_f32_16x16x32_bf16(pb, vb, o[dnt], 0, 0, 0);
            }
        }
        cur ^= 1;
    }
    // epilogue
    #pragma unroll
    for (int r = 0; r < 4; ++r) {
        float l = l_i[r];
        l += __shfl_xor(l, 1); l += __shfl_xor(l, 2);
        l += __shfl_xor(l, 4); l += __shfl_xor(l, 8);
        l_i[r] = 1.0f / l;
    }
    #pragma unroll
    for (int dnt = 0; dnt < 8; ++dnt) {
        #pragma unroll
        for (int r = 0; r < 4; ++r) {
            size_t row = (size_t)b * S_ + qrow0 + (quad << 2) + r;
            attn[row * D_ + h * DH_ + dnt * 16 + l16] = (bf16)(o[dnt][r] * l_i[r]);
        }
    }
}

// ---------------------------------------------------------------- launch
extern "C" void kernel_launch(void* const* d_in, const int* in_sizes, int n_in,
                              void* d_out, int out_size, void* d_ws, size_t ws_size,
                              hipStream_t stream) {
    const float* hidden = (const float*)d_in[0];
    const float* Wq  = (const float*)d_in[1];
    const float* Wk  = (const float*)d_in[2];
    const float* Wv  = (const float*)d_in[3];
    const float* Wo  = (const float*)d_in[4];
    const float* cqw = (const float*)d_in[5];
    const float* ckw = (const float*)d_in[6];
    const float* cvw = (const float*)d_in[7];
    const float* qnw = (const float*)d_in[8];
    const float* knw = (const float*)d_in[9];

    char* p = (char*)d_ws;
    auto alloc = [&](size_t bytes) { char* r = p; p += (bytes + 255) & ~(size_t)255; return r; };
    bf16*  X    = (bf16*)alloc((size_t)M_ * D_ * 2);
    bf16*  Wcat = (bf16*)alloc((size_t)NQKV_ * D_ * 2);
    bf16*  Wob  = (bf16*)alloc((size_t)D_ * D_ * 2);
    bf16*  QKV  = (bf16*)alloc((size_t)M_ * NQKV_ * 2);
    bf16*  qfb  = (bf16*)alloc((size_t)B_ * H_ * S_ * DH_ * 2);   // frag-linear Q
    bf16*  kfb  = (bf16*)alloc((size_t)B_ * KVH_ * S_ * DH_ * 2); // frag-linear K
    bf16*  vfr  = (bf16*)alloc((size_t)B_ * KVH_ * S_ * DH_ * 2); // frag-linear V
    float* cost = (float*)alloc((size_t)S_ * 64 * 4);
    float* sint = (float*)alloc((size_t)S_ * 64 * 4);
    bf16*  attnb = QKV;   // QKV dead after canon_kernel

    prep_kernel<<<20992, 256, 0, stream>>>(hidden, Wq, Wk, Wv, Wo, X, Wcat, Wob, cost, sint);
    gemm_bt8<<<(M_ / 256) * (NQKV_ / 256), 512, 0, stream>>>(X, Wcat, QKV, M_, NQKV_, D_);
    canon_kernel<<<1024, 256, 0, stream>>>(QKV, cqw, ckw, cvw, qnw, knw, cost, sint, qfb, kfb, vfr);
    flash_attn<<<1024, 256, 0, stream>>>(qfb, kfb, vfr, attnb);
    gemm_bt<float><<<dim3(D_ / BN, M_ / BM), 256, 0, stream>>>(attnb, Wob, (float*)d_out, M_, D_, D_);
}